// Round 11
// baseline (267.965 us; speedup 1.0000x reference)
//
#include <hip/hip_runtime.h>
#include <math.h>

// VectorQuantizer: N=131072 tokens, K=1024 codes, D=64, fp32.
// Out layout (flat): z_q_st[N*D] | loss | perplexity | indices[N] (as f32)
#define NTOK 131072
#define NEMB 1024
#define DIM  64
#define OUT_LOSS (NTOK * DIM)
#define OUT_PERP (OUT_LOSS + 1)
#define OUT_IDX  (OUT_LOSS + 2)

#define EPS_FLAG 6e-5f   // screen ambiguity margin (frozen; passed r3-r10)

typedef short bf16x8 __attribute__((ext_vector_type(8)));
typedef float f32x4  __attribute__((ext_vector_type(4)));

// ---- numpy fp32 semantics helpers (frozen from round 2 -- PASSED) ----------
__device__ __forceinline__ float sqb(float x) {
    float y = x * x;
    asm volatile("" : "+v"(y));
    return y;
}
// numpy pairwise_sum for n=64 contiguous: 8 accumulators stride 8, then
// ((r0+r1)+(r2+r3))+((r4+r5)+(r6+r7)).
#define NP_PAIRWISE_SQ64(GET, RES)                                     \
    do {                                                               \
        float r0 = sqb(GET(0)), r1 = sqb(GET(1)), r2 = sqb(GET(2)),    \
              r3 = sqb(GET(3)), r4 = sqb(GET(4)), r5 = sqb(GET(5)),    \
              r6 = sqb(GET(6)), r7 = sqb(GET(7));                      \
        _Pragma("unroll")                                              \
        for (int i = 8; i < 64; i += 8) {                              \
            r0 += sqb(GET(i + 0)); r1 += sqb(GET(i + 1));              \
            r2 += sqb(GET(i + 2)); r3 += sqb(GET(i + 3));              \
            r4 += sqb(GET(i + 4)); r5 += sqb(GET(i + 5));              \
            r6 += sqb(GET(i + 6)); r7 += sqb(GET(i + 7));              \
        }                                                              \
        RES = ((r0 + r1) + (r2 + r3)) + ((r4 + r5) + (r6 + r7));       \
    } while (0)

__device__ __forceinline__ unsigned short f2bf_rne(float x) {
    unsigned u = __float_as_uint(x);
    u += 0x7FFFu + ((u >> 16) & 1u);   // round-to-nearest-even
    return (unsigned short)(u >> 16);
}
__device__ __forceinline__ float bf2f(unsigned short b) {
    return __uint_as_float(((unsigned)b) << 16);
}

// ws layout (bytes):
//   0:      sse double
//   64:     counts int[1024]
//   4160:   qcount int
//   4168:   done int
//   4224:   h float[1024]
//   8320:   ch bf16[1024*64]   (128 KiB)
//   139392: cl bf16[1024*64]   (128 KiB)
//   270464: qlist int[NTOK]    (512 KiB)

// Kernel 0: h[k] np-exact; ch/cl bf16 split of (-2c); block 0 zeroes accums.
__global__ void vq_prep(const float* __restrict__ cb, float* __restrict__ h,
                        unsigned short* __restrict__ ch, unsigned short* __restrict__ cl,
                        double* __restrict__ sse, int* __restrict__ counts,
                        int* __restrict__ qcount, int* __restrict__ done) {
    if (blockIdx.x == 0) {
        if (threadIdx.x == 0) { *sse = 0.0; *qcount = 0; *done = 0; }
        for (int i = threadIdx.x; i < NEMB; i += 256) counts[i] = 0;
    }
    int k = blockIdx.x * 256 + threadIdx.x;
    if (k >= NEMB) return;
    float c[64];
    const float4* p = (const float4*)(cb + k * DIM);
#pragma unroll
    for (int q = 0; q < 16; ++q) {
        float4 v = p[q];
        c[4 * q] = v.x; c[4 * q + 1] = v.y; c[4 * q + 2] = v.z; c[4 * q + 3] = v.w;
    }
    float hk;
#define GETC(d) (c[d])
    NP_PAIRWISE_SQ64(GETC, hk);
#undef GETC
    h[k] = hk;
#pragma unroll
    for (int b = 0; b < 8; ++b) {
        unsigned uhv[4], ulv[4];
#pragma unroll
        for (int e = 0; e < 4; ++e) {
            float x0 = -2.0f * c[b * 8 + e * 2 + 0];
            float x1 = -2.0f * c[b * 8 + e * 2 + 1];
            unsigned short h0 = f2bf_rne(x0), h1 = f2bf_rne(x1);
            unsigned short l0 = f2bf_rne(x0 - bf2f(h0)), l1 = f2bf_rne(x1 - bf2f(h1));
            uhv[e] = (unsigned)h0 | ((unsigned)h1 << 16);
            ulv[e] = (unsigned)l0 | ((unsigned)l1 << 16);
        }
        *(uint4*)(ch + k * 64 + b * 8) = make_uint4(uhv[0], uhv[1], uhv[2], uhv[3]);
        *(uint4*)(cl + k * 64 + b * 8) = make_uint4(ulv[0], ulv[1], ulv[2], ulv[3]);
    }
}

// Kernel 1: MFMA screen v3 -- NO LDS, NO barriers in the main loop.
// A-fragments load directly from global ch/cl (L2-resident, coalesced:
// lane(col,grp) reads 16B at (K0+col)*128 + s*64 + grp*16). Same bytes as
// the old LDS path -> bit-identical MFMA inputs (frozen numerics r3-r10).
// 64 independent tile iterations; compiler pipelines loads freely.
__global__ __launch_bounds__(256) void vq_screen(
    const float*          __restrict__ ze,
    const float*          __restrict__ cb,
    const unsigned short* __restrict__ ch_g,
    const unsigned short* __restrict__ cl_g,
    const float*          __restrict__ h_g,
    float*                __restrict__ out,
    int*                  __restrict__ qcount,
    int*                  __restrict__ qlist,
    double*               __restrict__ sse_g,
    int*                  __restrict__ counts) {
    __shared__ double red[4];
    const int tid  = threadIdx.x;
    const int lane = tid & 63;
    const int wid  = tid >> 6;           // 0..3
    const int col  = lane & 15;
    const int grp  = lane >> 4;
    const int tbase = blockIdx.x * 128 + wid * 32;

    // z fragments (frozen)
    bf16x8 zh[2][2], zl[2][2];
#pragma unroll
    for (int tt = 0; tt < 2; ++tt)
#pragma unroll
        for (int s = 0; s < 2; ++s) {
            const float* zp = ze + (size_t)(tbase + tt * 16 + col) * 64 + s * 32 + grp * 8;
            float4 v0 = *(const float4*)(zp);
            float4 v1 = *(const float4*)(zp + 4);
            float zv[8] = {v0.x, v0.y, v0.z, v0.w, v1.x, v1.y, v1.z, v1.w};
            bf16x8 hfr, lfr;
#pragma unroll
            for (int j = 0; j < 8; ++j) {
                unsigned short hb = f2bf_rne(zv[j]);
                unsigned short lb = f2bf_rne(zv[j] - bf2f(hb));
                hfr[j] = (short)hb;
                lfr[j] = (short)lb;
            }
            zh[tt][s] = hfr;
            zl[tt][s] = lfr;
        }

    // per-j independent min slots (ILP)
    float s1[2][4], s2[2][4];
    int   sk[2][4];
#pragma unroll
    for (int tt = 0; tt < 2; ++tt)
#pragma unroll
        for (int j = 0; j < 4; ++j) {
            s1[tt][j] = INFINITY; s2[tt][j] = INFINITY; sk[tt][j] = 0;
        }

    // per-lane A-fragment base pointers (byte offsets within a 16-code tile)
    const char* chp = (const char*)ch_g + col * 128 + grp * 16;
    const char* clp = (const char*)cl_g + col * 128 + grp * 16;

#pragma unroll 2
    for (int kt = 0; kt < 64; ++kt) {
        const int kbyte = kt * 2048;   // 16 codes x 128 B
        bf16x8 ach0 = *(const bf16x8*)(chp + kbyte);        // s=0
        bf16x8 ach1 = *(const bf16x8*)(chp + kbyte + 64);   // s=1
        bf16x8 acl0 = *(const bf16x8*)(clp + kbyte);
        bf16x8 acl1 = *(const bf16x8*)(clp + kbyte + 64);
        f32x4 hv = *(const f32x4*)(h_g + kt * 16 + grp * 4);

        f32x4 acc0 = hv, acc1 = hv;
        acc0 = __builtin_amdgcn_mfma_f32_16x16x32_bf16(ach0, zh[0][0], acc0, 0, 0, 0);
        acc1 = __builtin_amdgcn_mfma_f32_16x16x32_bf16(ach0, zh[1][0], acc1, 0, 0, 0);
        acc0 = __builtin_amdgcn_mfma_f32_16x16x32_bf16(ach1, zh[0][1], acc0, 0, 0, 0);
        acc1 = __builtin_amdgcn_mfma_f32_16x16x32_bf16(ach1, zh[1][1], acc1, 0, 0, 0);
        acc0 = __builtin_amdgcn_mfma_f32_16x16x32_bf16(ach0, zl[0][0], acc0, 0, 0, 0);
        acc1 = __builtin_amdgcn_mfma_f32_16x16x32_bf16(ach0, zl[1][0], acc1, 0, 0, 0);
        acc0 = __builtin_amdgcn_mfma_f32_16x16x32_bf16(ach1, zl[0][1], acc0, 0, 0, 0);
        acc1 = __builtin_amdgcn_mfma_f32_16x16x32_bf16(ach1, zl[1][1], acc1, 0, 0, 0);
        acc0 = __builtin_amdgcn_mfma_f32_16x16x32_bf16(acl0, zh[0][0], acc0, 0, 0, 0);
        acc1 = __builtin_amdgcn_mfma_f32_16x16x32_bf16(acl0, zh[1][0], acc1, 0, 0, 0);
        acc0 = __builtin_amdgcn_mfma_f32_16x16x32_bf16(acl1, zh[0][1], acc0, 0, 0, 0);
        acc1 = __builtin_amdgcn_mfma_f32_16x16x32_bf16(acl1, zh[1][1], acc1, 0, 0, 0);

        const int kb = kt * 16 + grp * 4;
#pragma unroll
        for (int j = 0; j < 4; ++j) {
            float v0 = acc0[j], v1 = acc1[j];
            s2[0][j] = fminf(s2[0][j], fmaxf(v0, s1[0][j]));
            sk[0][j] = (v0 < s1[0][j]) ? (kb + j) : sk[0][j];
            s1[0][j] = fminf(s1[0][j], v0);
            s2[1][j] = fminf(s2[1][j], fmaxf(v1, s1[1][j]));
            sk[1][j] = (v1 < s1[1][j]) ? (kb + j) : sk[1][j];
            s1[1][j] = fminf(s1[1][j], v1);
        }
    }

    // merge the 4 slots (second-min merge formula)
    float m1[2], m2[2]; int ki[2];
#pragma unroll
    for (int tt = 0; tt < 2; ++tt) {
        m1[tt] = s1[tt][0]; m2[tt] = s2[tt][0]; ki[tt] = sk[tt][0];
#pragma unroll
        for (int j = 1; j < 4; ++j) {
            m2[tt] = fminf(fminf(m2[tt], s2[tt][j]), fmaxf(m1[tt], s1[tt][j]));
            ki[tt] = (s1[tt][j] < m1[tt]) ? sk[tt][j] : ki[tt];
            m1[tt] = fminf(m1[tt], s1[tt][j]);
        }
    }

    // cross-lane-group reduce (frozen)
#pragma unroll
    for (int d = 16; d <= 32; d <<= 1) {
#pragma unroll
        for (int tt = 0; tt < 2; ++tt) {
            float om1 = __shfl_xor(m1[tt], d, 64);
            float om2 = __shfl_xor(m2[tt], d, 64);
            int   oki = __shfl_xor(ki[tt], d, 64);
            m2[tt] = fminf(fminf(m2[tt], om2), fmaxf(m1[tt], om1));
            ki[tt] = (om1 < m1[tt]) ? oki : ki[tt];
            m1[tt] = fminf(m1[tt], om1);
        }
    }
    if (lane < 16) {
#pragma unroll
        for (int tt = 0; tt < 2; ++tt) {
            int t = tbase + tt * 16 + lane;
            out[OUT_IDX + t] = (float)ki[tt];
            if (m2[tt] - m1[tt] < EPS_FLAG) {
                int slot = atomicAdd(qcount, 1);
                qlist[slot] = t;
            }
        }
    }

    // fused gather / SSE / histogram epilogue (verified r7/r9/r10)
    double lsse = 0.0;
    for (int w = 0; w < 32; ++w) {
        const int tt = w >> 4, i = w & 15;
        const int idx = __shfl(ki[tt], i, 64);   // wave-uniform
        const int t = tbase + tt * 16 + i;
        float q  = cb[idx * 64 + lane];
        float zv = ze[(size_t)t * 64 + lane];
        out[(size_t)t * 64 + lane] = q;
        double diff = (double)q - (double)zv;
        lsse = fma(diff, diff, lsse);
        if (lane == 0) atomicAdd(&counts[idx], 1);
    }
#pragma unroll
    for (int off = 32; off > 0; off >>= 1)
        lsse += __shfl_down(lsse, off, 64);
    if (lane == 0) red[wid] = lsse;
    __syncthreads();
    if (tid == 0) {
        double bs = (red[0] + red[1]) + (red[2] + red[3]);
        atomicAdd(sse_g, bs);
    }
}

// Kernel 2: correction rescue (LDS-staged scan, r8-r10 PASSED) + last-block
// finalize. Byte-frozen from r10.
__global__ __launch_bounds__(512) void vq_rescue(
    const float* __restrict__ ze, const float* __restrict__ cb,
    const float* __restrict__ h_g, const int* __restrict__ qcount,
    const int* __restrict__ qlist, float* __restrict__ out,
    double* __restrict__ sse_g, int* __restrict__ counts,
    int* __restrict__ done) {
    __shared__ __align__(16) float4 cbl[512 * 17];          // 139,264 B
    __shared__ float zst[8][64];
    __shared__ unsigned long long keys[8][64];
    __shared__ float hl[NEMB];
    __shared__ int flagS;
    const int tid  = threadIdx.x;
    const int lane = tid & 63;
    const int wid  = tid >> 6;
    const int nq   = *qcount;
    const int per  = (nq + 255) >> 8;
    const int i0   = blockIdx.x * per;
    const int iend = (i0 + per < nq) ? (i0 + per) : nq;

    if (i0 < iend) {   // block-uniform
        for (int i = tid; i < NEMB; i += 512) hl[i] = h_g[i];
        const float4* cb4 = (const float4*)cb;

        for (int hf = 0; hf < 2; ++hf) {
            __syncthreads();
#pragma unroll
            for (int j = 0; j < 16; ++j) {
                int f = tid + j * 512;
                int code = f >> 4, d4 = f & 15;
                cbl[code * 17 + d4] = cb4[(size_t)(hf * 512 + code) * 16 + d4];
            }
            __syncthreads();

            for (int i = i0 + wid; i < iend; i += 8) {
                const int t = qlist[i];
                const int slot = (i - i0) >> 3;

                zst[wid][lane] = ze[(size_t)t * 64 + lane];
                __builtin_amdgcn_wave_barrier();
                asm volatile("s_waitcnt lgkmcnt(0)" ::: "memory");
                __builtin_amdgcn_sched_barrier(0);

                float sz;
#define GZ(d) (zst[wid][d])
                NP_PAIRWISE_SQ64(GZ, sz);
#undef GZ

                float acc[8] = {0.f, 0.f, 0.f, 0.f, 0.f, 0.f, 0.f, 0.f};
                const float4* zr4 = (const float4*)zst[wid];
#pragma unroll
                for (int d4 = 0; d4 < 16; ++d4) {
                    float4 zq = zr4[d4];
#pragma unroll
                    for (int cc = 0; cc < 8; ++cc) {
                        float4 cv = cbl[(lane + 64 * cc) * 17 + d4];
                        acc[cc] = fmaf(cv.x, zq.x, acc[cc]);
                        acc[cc] = fmaf(cv.y, zq.y, acc[cc]);
                        acc[cc] = fmaf(cv.z, zq.z, acc[cc]);
                        acc[cc] = fmaf(cv.w, zq.w, acc[cc]);
                    }
                }
                unsigned long long key = ~0ull;
#pragma unroll
                for (int cc = 0; cc < 8; ++cc) {
                    unsigned k = (unsigned)(hf * 512 + lane + 64 * cc);
                    float dk = (sz + hl[k]) - 2.0f * acc[cc];   // frozen formula
                    unsigned long long c =
                        ((unsigned long long)__float_as_uint(dk) << 32) | k;
                    key = c < key ? c : key;
                }
#pragma unroll
                for (int dd = 1; dd < 64; dd <<= 1) {
                    unsigned long long o = __shfl_xor(key, dd, 64);
                    key = o < key ? o : key;
                }
                if (hf == 0) {
                    if (lane == 0) keys[wid][slot] = key;
                } else {
                    unsigned long long k0 = keys[wid][slot];  // LDS broadcast
                    if (k0 < key) key = k0;
                    int newk = (int)(unsigned)(key & 0xFFFFFFFFull);
                    int scrk = (int)out[OUT_IDX + t];
                    if (newk != scrk) {
                        float zv = zst[wid][lane];
                        float qo = cb[scrk * 64 + lane];
                        float qn = cb[newk * 64 + lane];
                        out[(size_t)t * 64 + lane] = qn;
                        double dn = (double)qn - (double)zv;
                        double dd2 = (double)qo - (double)zv;
                        double delta = dn * dn - dd2 * dd2;
#pragma unroll
                        for (int off = 32; off > 0; off >>= 1)
                            delta += __shfl_down(delta, off, 64);
                        if (lane == 0) {
                            out[OUT_IDX + t] = (float)newk;
                            atomicAdd(sse_g, delta);
                            atomicAdd(&counts[scrk], -1);
                            atomicAdd(&counts[newk], 1);
                        }
                    }
                }
            }
        }
    }

    // all 256 blocks: done-counter; last block finalizes loss + perplexity
    __syncthreads();
    __threadfence();
    if (tid == 0) flagS = (atomicAdd(done, 1) == 255);
    __syncthreads();
    if (flagS) {
        __threadfence();
        double* red2 = (double*)cbl;   // staging LDS dead here
        double local = 0.0;
        for (int k = tid; k < NEMB; k += 512) {
            int cv = __hip_atomic_load(&counts[k], __ATOMIC_RELAXED, __HIP_MEMORY_SCOPE_AGENT);
            double p = (double)cv / (double)NTOK;
            local += p * log(p + 1e-10);
        }
        red2[tid] = local;
        __syncthreads();
        for (int s = 256; s > 0; s >>= 1) {
            if (tid < s) red2[tid] += red2[tid + s];
            __syncthreads();
        }
        if (tid == 0) {
            double sv = __hip_atomic_load(sse_g, __ATOMIC_RELAXED, __HIP_MEMORY_SCOPE_AGENT);
            double mse = sv / ((double)NTOK * (double)DIM);
            out[OUT_LOSS] = (float)(1.25 * mse);
            out[OUT_PERP] = (float)exp(-red2[0]);
        }
    }
}

extern "C" void kernel_launch(void* const* d_in, const int* in_sizes, int n_in,
                              void* d_out, int out_size, void* d_ws, size_t ws_size,
                              hipStream_t stream) {
    const float* ze = (const float*)d_in[0];
    const float* cb = (const float*)d_in[1];
    float* out = (float*)d_out;

    char* w = (char*)d_ws;
    double*         sse    = (double*)w;                    // @0
    int*            counts = (int*)(w + 64);                // @64    (4 KiB)
    int*            qcount = (int*)(w + 4160);              // @4160
    int*            done   = (int*)(w + 4168);              // @4168
    float*          h      = (float*)(w + 4224);            // @4224  (4 KiB)
    unsigned short* ch     = (unsigned short*)(w + 8320);   // 128 KiB
    unsigned short* cl     = (unsigned short*)(w + 139392); // 128 KiB
    int*            qlist  = (int*)(w + 270464);            // 512 KiB

    vq_prep<<<NEMB / 256, 256, 0, stream>>>(cb, h, ch, cl, sse, counts, qcount, done);
    vq_screen<<<NTOK / 128, 256, 0, stream>>>(ze, cb, ch, cl, h, out, qcount, qlist, sse, counts);
    vq_rescue<<<256, 512, 0, stream>>>(ze, cb, h, qcount, qlist, out, sse, counts, done);
}

// Round 12
// 229.582 us; speedup vs baseline: 1.1672x; 1.1672x over previous
//
#include <hip/hip_runtime.h>
#include <math.h>

// VectorQuantizer: N=131072 tokens, K=1024 codes, D=64, fp32.
// Out layout (flat): z_q_st[N*D] | loss | perplexity | indices[N] (as f32)
#define NTOK 131072
#define NEMB 1024
#define DIM  64
#define OUT_LOSS (NTOK * DIM)
#define OUT_PERP (OUT_LOSS + 1)
#define OUT_IDX  (OUT_LOSS + 2)

#define EPS_FLAG 6e-5f   // screen ambiguity margin (frozen; passed r3-r11)

typedef short bf16x8 __attribute__((ext_vector_type(8)));
typedef float f32x4  __attribute__((ext_vector_type(4)));

// ---- numpy fp32 semantics helpers (frozen from round 2 -- PASSED) ----------
__device__ __forceinline__ float sqb(float x) {
    float y = x * x;
    asm volatile("" : "+v"(y));
    return y;
}
// numpy pairwise_sum for n=64 contiguous: 8 accumulators stride 8, then
// ((r0+r1)+(r2+r3))+((r4+r5)+(r6+r7)).
#define NP_PAIRWISE_SQ64(GET, RES)                                     \
    do {                                                               \
        float r0 = sqb(GET(0)), r1 = sqb(GET(1)), r2 = sqb(GET(2)),    \
              r3 = sqb(GET(3)), r4 = sqb(GET(4)), r5 = sqb(GET(5)),    \
              r6 = sqb(GET(6)), r7 = sqb(GET(7));                      \
        _Pragma("unroll")                                              \
        for (int i = 8; i < 64; i += 8) {                              \
            r0 += sqb(GET(i + 0)); r1 += sqb(GET(i + 1));              \
            r2 += sqb(GET(i + 2)); r3 += sqb(GET(i + 3));              \
            r4 += sqb(GET(i + 4)); r5 += sqb(GET(i + 5));              \
            r6 += sqb(GET(i + 6)); r7 += sqb(GET(i + 7));              \
        }                                                              \
        RES = ((r0 + r1) + (r2 + r3)) + ((r4 + r5) + (r6 + r7));       \
    } while (0)

__device__ __forceinline__ unsigned short f2bf_rne(float x) {
    unsigned u = __float_as_uint(x);
    u += 0x7FFFu + ((u >> 16) & 1u);   // round-to-nearest-even
    return (unsigned short)(u >> 16);
}
__device__ __forceinline__ float bf2f(unsigned short b) {
    return __uint_as_float(((unsigned)b) << 16);
}

// ws layout (bytes):
//   0:      sse double
//   64:     counts int[1024]
//   4160:   qcount int
//   4168:   done int
//   4224:   h float[1024]
//   8320:   ch bf16[1024*64]   (128 KiB)
//   139392: cl bf16[1024*64]   (128 KiB)
//   270464: qlist int[NTOK]    (512 KiB)

// Kernel 0: h[k] np-exact; ch/cl bf16 split of (-2c); block 0 zeroes accums.
__global__ void vq_prep(const float* __restrict__ cb, float* __restrict__ h,
                        unsigned short* __restrict__ ch, unsigned short* __restrict__ cl,
                        double* __restrict__ sse, int* __restrict__ counts,
                        int* __restrict__ qcount, int* __restrict__ done) {
    if (blockIdx.x == 0) {
        if (threadIdx.x == 0) { *sse = 0.0; *qcount = 0; *done = 0; }
        for (int i = threadIdx.x; i < NEMB; i += 256) counts[i] = 0;
    }
    int k = blockIdx.x * 256 + threadIdx.x;
    if (k >= NEMB) return;
    float c[64];
    const float4* p = (const float4*)(cb + k * DIM);
#pragma unroll
    for (int q = 0; q < 16; ++q) {
        float4 v = p[q];
        c[4 * q] = v.x; c[4 * q + 1] = v.y; c[4 * q + 2] = v.z; c[4 * q + 3] = v.w;
    }
    float hk;
#define GETC(d) (c[d])
    NP_PAIRWISE_SQ64(GETC, hk);
#undef GETC
    h[k] = hk;
#pragma unroll
    for (int b = 0; b < 8; ++b) {
        unsigned uhv[4], ulv[4];
#pragma unroll
        for (int e = 0; e < 4; ++e) {
            float x0 = -2.0f * c[b * 8 + e * 2 + 0];
            float x1 = -2.0f * c[b * 8 + e * 2 + 1];
            unsigned short h0 = f2bf_rne(x0), h1 = f2bf_rne(x1);
            unsigned short l0 = f2bf_rne(x0 - bf2f(h0)), l1 = f2bf_rne(x1 - bf2f(h1));
            uhv[e] = (unsigned)h0 | ((unsigned)h1 << 16);
            ulv[e] = (unsigned)l0 | ((unsigned)l1 << 16);
        }
        *(uint4*)(ch + k * 64 + b * 8) = make_uint4(uhv[0], uhv[1], uhv[2], uhv[3]);
        *(uint4*)(cl + k * 64 + b * 8) = make_uint4(ulv[0], ulv[1], ulv[2], ulv[3]);
    }
}

// Kernel 1: MFMA screen v4 -- r9 LDS structure, chunk = 128 codes:
// 8 double-buffered phases (was 16), 2x32KB LDS + h = ~66KB -> 2 blocks/CU.
// Same staged bytes / swizzle / ds_read pattern -> bit-identical MFMA inputs
// (frozen numerics r3-r11). Fused gather/SSE/histogram epilogue (r9).
__global__ __launch_bounds__(512) void vq_screen(
    const float*          __restrict__ ze,
    const float*          __restrict__ cb,
    const unsigned short* __restrict__ ch_g,
    const unsigned short* __restrict__ cl_g,
    const float*          __restrict__ h_g,
    float*                __restrict__ out,
    int*                  __restrict__ qcount,
    int*                  __restrict__ qlist,
    double*               __restrict__ sse_g,
    int*                  __restrict__ counts) {
    // LDS: 2 buffers x (16KB ch + 16KB cl) | h 2x512B | red 64B
    __shared__ __align__(16) char lds[65536 + 1024 + 64];
    const int tid  = threadIdx.x;
    const int lane = tid & 63;
    const int wid  = tid >> 6;           // 0..7
    const int col  = lane & 15;
    const int grp  = lane >> 4;
    const int tbase = blockIdx.x * 256 + wid * 32;

    // z fragments (frozen)
    bf16x8 zh[2][2], zl[2][2];
#pragma unroll
    for (int tt = 0; tt < 2; ++tt)
#pragma unroll
        for (int s = 0; s < 2; ++s) {
            const float* zp = ze + (size_t)(tbase + tt * 16 + col) * 64 + s * 32 + grp * 8;
            float4 v0 = *(const float4*)(zp);
            float4 v1 = *(const float4*)(zp + 4);
            float zv[8] = {v0.x, v0.y, v0.z, v0.w, v1.x, v1.y, v1.z, v1.w};
            bf16x8 hfr, lfr;
#pragma unroll
            for (int j = 0; j < 8; ++j) {
                unsigned short hb = f2bf_rne(zv[j]);
                unsigned short lb = f2bf_rne(zv[j] - bf2f(hb));
                hfr[j] = (short)hb;
                lfr[j] = (short)lb;
            }
            zh[tt][s] = hfr;
            zl[tt][s] = lfr;
        }

    // per-j independent min slots (ILP)
    float s1[2][4], s2[2][4];
    int   sk[2][4];
#pragma unroll
    for (int tt = 0; tt < 2; ++tt)
#pragma unroll
        for (int j = 0; j < 4; ++j) {
            s1[tt][j] = INFINITY; s2[tt][j] = INFINITY; sk[tt][j] = 0;
        }

    // T14 split staging: chunk = 128 codes = 1024 int4 per array;
    // thread handles int4 indices {tid, tid+512} for ch and cl.
    int4 va0, va1, vb0, vb1; float hval = 0.f;
#define LOADR(cc)                                                                \
    do {                                                                         \
        va0 = *(const int4*)((const char*)ch_g + (cc) * 16384 + tid * 16);       \
        va1 = *(const int4*)((const char*)ch_g + (cc) * 16384 + (tid + 512) * 16); \
        vb0 = *(const int4*)((const char*)cl_g + (cc) * 16384 + tid * 16);       \
        vb1 = *(const int4*)((const char*)cl_g + (cc) * 16384 + (tid + 512) * 16); \
        if (tid < 128) hval = h_g[(cc) * 128 + tid];                             \
    } while (0)
#define WRITE1(b, i, va, vb)                                                     \
    do {                                                                         \
        int r = (i) >> 3, slot = (i) & 7;                                        \
        int st = r >> 4, row = r & 15;                                           \
        int off = (b) * 32768 + st * 2048 + row * 128 + ((slot ^ (row & 7)) << 4); \
        *(int4*)(lds + off) = va;                                                \
        *(int4*)(lds + off + 16384) = vb;                                        \
    } while (0)
#define WRITER(b)                                                                \
    do {                                                                         \
        WRITE1(b, tid, va0, vb0);                                                \
        WRITE1(b, tid + 512, va1, vb1);                                          \
        if (tid < 128) *(float*)(lds + 65536 + (b) * 512 + tid * 4) = hval;      \
    } while (0)

    LOADR(0); WRITER(0);
    __syncthreads();

    for (int cc = 0; cc < 8; ++cc) {
        int b = cc & 1;
        if (cc < 7) LOADR(cc + 1);   // issue early (hidden under MFMA phase)

        for (int ct = 0; ct < 8; ++ct) {
            const int arow = b * 32768 + ct * 2048 + col * 128;
            bf16x8 ach0 = *(const bf16x8*)(lds + arow + ((((0 * 4) + grp) ^ (col & 7)) << 4));
            bf16x8 ach1 = *(const bf16x8*)(lds + arow + ((((1 * 4) + grp) ^ (col & 7)) << 4));
            bf16x8 acl0 = *(const bf16x8*)(lds + arow + 16384 + ((((0 * 4) + grp) ^ (col & 7)) << 4));
            bf16x8 acl1 = *(const bf16x8*)(lds + arow + 16384 + ((((1 * 4) + grp) ^ (col & 7)) << 4));
            f32x4 hv = *(const f32x4*)(lds + 65536 + b * 512 + ct * 64 + grp * 16);

            f32x4 acc0 = hv, acc1 = hv;
            acc0 = __builtin_amdgcn_mfma_f32_16x16x32_bf16(ach0, zh[0][0], acc0, 0, 0, 0);
            acc1 = __builtin_amdgcn_mfma_f32_16x16x32_bf16(ach0, zh[1][0], acc1, 0, 0, 0);
            acc0 = __builtin_amdgcn_mfma_f32_16x16x32_bf16(ach1, zh[0][1], acc0, 0, 0, 0);
            acc1 = __builtin_amdgcn_mfma_f32_16x16x32_bf16(ach1, zh[1][1], acc1, 0, 0, 0);
            acc0 = __builtin_amdgcn_mfma_f32_16x16x32_bf16(ach0, zl[0][0], acc0, 0, 0, 0);
            acc1 = __builtin_amdgcn_mfma_f32_16x16x32_bf16(ach0, zl[1][0], acc1, 0, 0, 0);
            acc0 = __builtin_amdgcn_mfma_f32_16x16x32_bf16(ach1, zl[0][1], acc0, 0, 0, 0);
            acc1 = __builtin_amdgcn_mfma_f32_16x16x32_bf16(ach1, zl[1][1], acc1, 0, 0, 0);
            acc0 = __builtin_amdgcn_mfma_f32_16x16x32_bf16(acl0, zh[0][0], acc0, 0, 0, 0);
            acc1 = __builtin_amdgcn_mfma_f32_16x16x32_bf16(acl0, zh[1][0], acc1, 0, 0, 0);
            acc0 = __builtin_amdgcn_mfma_f32_16x16x32_bf16(acl1, zh[0][1], acc0, 0, 0, 0);
            acc1 = __builtin_amdgcn_mfma_f32_16x16x32_bf16(acl1, zh[1][1], acc1, 0, 0, 0);

            const int kb = cc * 128 + ct * 16 + grp * 4;
#pragma unroll
            for (int j = 0; j < 4; ++j) {
                float v0 = acc0[j], v1 = acc1[j];
                s2[0][j] = fminf(s2[0][j], fmaxf(v0, s1[0][j]));
                sk[0][j] = (v0 < s1[0][j]) ? (kb + j) : sk[0][j];
                s1[0][j] = fminf(s1[0][j], v0);
                s2[1][j] = fminf(s2[1][j], fmaxf(v1, s1[1][j]));
                sk[1][j] = (v1 < s1[1][j]) ? (kb + j) : sk[1][j];
                s1[1][j] = fminf(s1[1][j], v1);
            }
        }
        if (cc < 7) WRITER(b ^ 1);   // vmcnt wait here, after compute
        __syncthreads();
    }

    // merge the 4 slots (second-min merge formula)
    float m1[2], m2[2]; int ki[2];
#pragma unroll
    for (int tt = 0; tt < 2; ++tt) {
        m1[tt] = s1[tt][0]; m2[tt] = s2[tt][0]; ki[tt] = sk[tt][0];
#pragma unroll
        for (int j = 1; j < 4; ++j) {
            m2[tt] = fminf(fminf(m2[tt], s2[tt][j]), fmaxf(m1[tt], s1[tt][j]));
            ki[tt] = (s1[tt][j] < m1[tt]) ? sk[tt][j] : ki[tt];
            m1[tt] = fminf(m1[tt], s1[tt][j]);
        }
    }

    // cross-lane-group reduce (frozen)
#pragma unroll
    for (int d = 16; d <= 32; d <<= 1) {
#pragma unroll
        for (int tt = 0; tt < 2; ++tt) {
            float om1 = __shfl_xor(m1[tt], d, 64);
            float om2 = __shfl_xor(m2[tt], d, 64);
            int   oki = __shfl_xor(ki[tt], d, 64);
            m2[tt] = fminf(fminf(m2[tt], om2), fmaxf(m1[tt], om1));
            ki[tt] = (om1 < m1[tt]) ? oki : ki[tt];
            m1[tt] = fminf(m1[tt], om1);
        }
    }
    if (lane < 16) {
#pragma unroll
        for (int tt = 0; tt < 2; ++tt) {
            int t = tbase + tt * 16 + lane;
            out[OUT_IDX + t] = (float)ki[tt];
            if (m2[tt] - m1[tt] < EPS_FLAG) {
                int slot = atomicAdd(qcount, 1);
                qlist[slot] = t;
            }
        }
    }

    // fused gather / SSE / histogram epilogue (verified r7/r9/r10/r11)
    double lsse = 0.0;
    for (int w = 0; w < 32; ++w) {
        const int tt = w >> 4, i = w & 15;
        const int idx = __shfl(ki[tt], i, 64);   // wave-uniform
        const int t = tbase + tt * 16 + i;
        float q  = cb[idx * 64 + lane];
        float zv = ze[(size_t)t * 64 + lane];
        out[(size_t)t * 64 + lane] = q;
        double diff = (double)q - (double)zv;
        lsse = fma(diff, diff, lsse);
        if (lane == 0) atomicAdd(&counts[idx], 1);
    }
#pragma unroll
    for (int off = 32; off > 0; off >>= 1)
        lsse += __shfl_down(lsse, off, 64);
    double* red = (double*)(lds + 66560);
    if (lane == 0) red[wid] = lsse;
    __syncthreads();
    if (tid == 0) {
        double bs = ((red[0] + red[1]) + (red[2] + red[3]))
                  + ((red[4] + red[5]) + (red[6] + red[7]));
        atomicAdd(sse_g, bs);
    }
}

// Kernel 2: correction rescue (LDS-staged scan) + last-block finalize.
// r12 change: 64 blocks (was 256) -> codebook staging traffic /4 (~16MB);
// ~91 tokens/block keeps waves busy. Logic byte-frozen from r10/r11.
__global__ __launch_bounds__(512) void vq_rescue(
    const float* __restrict__ ze, const float* __restrict__ cb,
    const float* __restrict__ h_g, const int* __restrict__ qcount,
    const int* __restrict__ qlist, float* __restrict__ out,
    double* __restrict__ sse_g, int* __restrict__ counts,
    int* __restrict__ done) {
    __shared__ __align__(16) float4 cbl[512 * 17];          // 139,264 B
    __shared__ float zst[8][64];
    __shared__ unsigned long long keys[8][128];
    __shared__ float hl[NEMB];
    __shared__ int flagS;
    const int tid  = threadIdx.x;
    const int lane = tid & 63;
    const int wid  = tid >> 6;
    const int nq   = *qcount;
    const int per  = (nq + 63) >> 6;
    const int i0   = blockIdx.x * per;
    const int iend = (i0 + per < nq) ? (i0 + per) : nq;

    if (i0 < iend) {   // block-uniform
        for (int i = tid; i < NEMB; i += 512) hl[i] = h_g[i];
        const float4* cb4 = (const float4*)cb;

        for (int hf = 0; hf < 2; ++hf) {
            __syncthreads();
#pragma unroll
            for (int j = 0; j < 16; ++j) {
                int f = tid + j * 512;
                int code = f >> 4, d4 = f & 15;
                cbl[code * 17 + d4] = cb4[(size_t)(hf * 512 + code) * 16 + d4];
            }
            __syncthreads();

            for (int i = i0 + wid; i < iend; i += 8) {
                const int t = qlist[i];
                const int slot = (i - i0) >> 3;

                zst[wid][lane] = ze[(size_t)t * 64 + lane];
                __builtin_amdgcn_wave_barrier();
                asm volatile("s_waitcnt lgkmcnt(0)" ::: "memory");
                __builtin_amdgcn_sched_barrier(0);

                float sz;
#define GZ(d) (zst[wid][d])
                NP_PAIRWISE_SQ64(GZ, sz);
#undef GZ

                float acc[8] = {0.f, 0.f, 0.f, 0.f, 0.f, 0.f, 0.f, 0.f};
                const float4* zr4 = (const float4*)zst[wid];
#pragma unroll
                for (int d4 = 0; d4 < 16; ++d4) {
                    float4 zq = zr4[d4];
#pragma unroll
                    for (int cc = 0; cc < 8; ++cc) {
                        float4 cv = cbl[(lane + 64 * cc) * 17 + d4];
                        acc[cc] = fmaf(cv.x, zq.x, acc[cc]);
                        acc[cc] = fmaf(cv.y, zq.y, acc[cc]);
                        acc[cc] = fmaf(cv.z, zq.z, acc[cc]);
                        acc[cc] = fmaf(cv.w, zq.w, acc[cc]);
                    }
                }
                unsigned long long key = ~0ull;
#pragma unroll
                for (int cc = 0; cc < 8; ++cc) {
                    unsigned k = (unsigned)(hf * 512 + lane + 64 * cc);
                    float dk = (sz + hl[k]) - 2.0f * acc[cc];   // frozen formula
                    unsigned long long c =
                        ((unsigned long long)__float_as_uint(dk) << 32) | k;
                    key = c < key ? c : key;
                }
#pragma unroll
                for (int dd = 1; dd < 64; dd <<= 1) {
                    unsigned long long o = __shfl_xor(key, dd, 64);
                    key = o < key ? o : key;
                }
                if (hf == 0) {
                    if (lane == 0) keys[wid][slot] = key;
                } else {
                    unsigned long long k0 = keys[wid][slot];  // LDS broadcast
                    if (k0 < key) key = k0;
                    int newk = (int)(unsigned)(key & 0xFFFFFFFFull);
                    int scrk = (int)out[OUT_IDX + t];
                    if (newk != scrk) {
                        float zv = zst[wid][lane];
                        float qo = cb[scrk * 64 + lane];
                        float qn = cb[newk * 64 + lane];
                        out[(size_t)t * 64 + lane] = qn;
                        double dn = (double)qn - (double)zv;
                        double dd2 = (double)qo - (double)zv;
                        double delta = dn * dn - dd2 * dd2;
#pragma unroll
                        for (int off = 32; off > 0; off >>= 1)
                            delta += __shfl_down(delta, off, 64);
                        if (lane == 0) {
                            out[OUT_IDX + t] = (float)newk;
                            atomicAdd(sse_g, delta);
                            atomicAdd(&counts[scrk], -1);
                            atomicAdd(&counts[newk], 1);
                        }
                    }
                }
            }
        }
    }

    // all 64 blocks: done-counter; last block finalizes loss + perplexity
    __syncthreads();
    __threadfence();
    if (tid == 0) flagS = (atomicAdd(done, 1) == 63);
    __syncthreads();
    if (flagS) {
        __threadfence();
        double* red2 = (double*)cbl;   // staging LDS dead here
        double local = 0.0;
        for (int k = tid; k < NEMB; k += 512) {
            int cv = __hip_atomic_load(&counts[k], __ATOMIC_RELAXED, __HIP_MEMORY_SCOPE_AGENT);
            double p = (double)cv / (double)NTOK;
            local += p * log(p + 1e-10);
        }
        red2[tid] = local;
        __syncthreads();
        for (int s = 256; s > 0; s >>= 1) {
            if (tid < s) red2[tid] += red2[tid + s];
            __syncthreads();
        }
        if (tid == 0) {
            double sv = __hip_atomic_load(sse_g, __ATOMIC_RELAXED, __HIP_MEMORY_SCOPE_AGENT);
            double mse = sv / ((double)NTOK * (double)DIM);
            out[OUT_LOSS] = (float)(1.25 * mse);
            out[OUT_PERP] = (float)exp(-red2[0]);
        }
    }
}

extern "C" void kernel_launch(void* const* d_in, const int* in_sizes, int n_in,
                              void* d_out, int out_size, void* d_ws, size_t ws_size,
                              hipStream_t stream) {
    const float* ze = (const float*)d_in[0];
    const float* cb = (const float*)d_in[1];
    float* out = (float*)d_out;

    char* w = (char*)d_ws;
    double*         sse    = (double*)w;                    // @0
    int*            counts = (int*)(w + 64);                // @64    (4 KiB)
    int*            qcount = (int*)(w + 4160);              // @4160
    int*            done   = (int*)(w + 4168);              // @4168
    float*          h      = (float*)(w + 4224);            // @4224  (4 KiB)
    unsigned short* ch     = (unsigned short*)(w + 8320);   // 128 KiB
    unsigned short* cl     = (unsigned short*)(w + 139392); // 128 KiB
    int*            qlist  = (int*)(w + 270464);            // 512 KiB

    vq_prep<<<NEMB / 256, 256, 0, stream>>>(cb, h, ch, cl, sse, counts, qcount, done);
    vq_screen<<<NTOK / 256, 512, 0, stream>>>(ze, cb, ch, cl, h, out, qcount, qlist, sse, counts);
    vq_rescue<<<64, 512, 0, stream>>>(ze, cb, h, qcount, qlist, out, sse, counts, done);
}

// Round 13
// 189.834 us; speedup vs baseline: 1.4116x; 1.2094x over previous
//
#include <hip/hip_runtime.h>
#include <math.h>

// VectorQuantizer: N=131072 tokens, K=1024 codes, D=64, fp32.
// Out layout (flat): z_q_st[N*D] | loss | perplexity | indices[N] (as f32)
#define NTOK 131072
#define NEMB 1024
#define DIM  64
#define OUT_LOSS (NTOK * DIM)
#define OUT_PERP (OUT_LOSS + 1)
#define OUT_IDX  (OUT_LOSS + 2)

#define EPS_FLAG 6e-5f   // screen ambiguity margin (frozen; passed r3-r12)

typedef short bf16x8 __attribute__((ext_vector_type(8)));
typedef float f32x4  __attribute__((ext_vector_type(4)));

// ---- numpy fp32 semantics helpers (frozen from round 2 -- PASSED) ----------
__device__ __forceinline__ float sqb(float x) {
    float y = x * x;
    asm volatile("" : "+v"(y));
    return y;
}
// numpy pairwise_sum for n=64 contiguous: 8 accumulators stride 8, then
// ((r0+r1)+(r2+r3))+((r4+r5)+(r6+r7)).
#define NP_PAIRWISE_SQ64(GET, RES)                                     \
    do {                                                               \
        float r0 = sqb(GET(0)), r1 = sqb(GET(1)), r2 = sqb(GET(2)),    \
              r3 = sqb(GET(3)), r4 = sqb(GET(4)), r5 = sqb(GET(5)),    \
              r6 = sqb(GET(6)), r7 = sqb(GET(7));                      \
        _Pragma("unroll")                                              \
        for (int i = 8; i < 64; i += 8) {                              \
            r0 += sqb(GET(i + 0)); r1 += sqb(GET(i + 1));              \
            r2 += sqb(GET(i + 2)); r3 += sqb(GET(i + 3));              \
            r4 += sqb(GET(i + 4)); r5 += sqb(GET(i + 5));              \
            r6 += sqb(GET(i + 6)); r7 += sqb(GET(i + 7));              \
        }                                                              \
        RES = ((r0 + r1) + (r2 + r3)) + ((r4 + r5) + (r6 + r7));       \
    } while (0)

__device__ __forceinline__ unsigned short f2bf_rne(float x) {
    unsigned u = __float_as_uint(x);
    u += 0x7FFFu + ((u >> 16) & 1u);   // round-to-nearest-even
    return (unsigned short)(u >> 16);
}
__device__ __forceinline__ float bf2f(unsigned short b) {
    return __uint_as_float(((unsigned)b) << 16);
}

// ws layout (bytes):
//   0:      sse double
//   64:     counts int[1024]
//   4160:   done int
//   4224:   h float[1024]
//   8320:   ch bf16[1024*64]   (128 KiB)
//   139392: cl bf16[1024*64]   (128 KiB)

// Kernel 0: h[k] np-exact; ch/cl bf16 split of (-2c); block 0 zeroes accums.
__global__ void vq_prep(const float* __restrict__ cb, float* __restrict__ h,
                        unsigned short* __restrict__ ch, unsigned short* __restrict__ cl,
                        double* __restrict__ sse, int* __restrict__ counts,
                        int* __restrict__ done) {
    if (blockIdx.x == 0) {
        if (threadIdx.x == 0) { *sse = 0.0; *done = 0; }
        for (int i = threadIdx.x; i < NEMB; i += 256) counts[i] = 0;
    }
    int k = blockIdx.x * 256 + threadIdx.x;
    if (k >= NEMB) return;
    float c[64];
    const float4* p = (const float4*)(cb + k * DIM);
#pragma unroll
    for (int q = 0; q < 16; ++q) {
        float4 v = p[q];
        c[4 * q] = v.x; c[4 * q + 1] = v.y; c[4 * q + 2] = v.z; c[4 * q + 3] = v.w;
    }
    float hk;
#define GETC(d) (c[d])
    NP_PAIRWISE_SQ64(GETC, hk);
#undef GETC
    h[k] = hk;
#pragma unroll
    for (int b = 0; b < 8; ++b) {
        unsigned uhv[4], ulv[4];
#pragma unroll
        for (int e = 0; e < 4; ++e) {
            float x0 = -2.0f * c[b * 8 + e * 2 + 0];
            float x1 = -2.0f * c[b * 8 + e * 2 + 1];
            unsigned short h0 = f2bf_rne(x0), h1 = f2bf_rne(x1);
            unsigned short l0 = f2bf_rne(x0 - bf2f(h0)), l1 = f2bf_rne(x1 - bf2f(h1));
            uhv[e] = (unsigned)h0 | ((unsigned)h1 << 16);
            ulv[e] = (unsigned)l0 | ((unsigned)l1 << 16);
        }
        *(uint4*)(ch + k * 64 + b * 8) = make_uint4(uhv[0], uhv[1], uhv[2], uhv[3]);
        *(uint4*)(cl + k * 64 + b * 8) = make_uint4(ulv[0], ulv[1], ulv[2], ulv[3]);
    }
}

// Kernel 1: MFMA screen -- r8 structure VERBATIM (fastest measured: 80us).
// Only change: ambiguity flag goes in the SIGN of the idx float (r3-proven);
// no qlist/qcount, no epilogue.
__global__ __launch_bounds__(512) void vq_screen(
    const float*          __restrict__ ze,
    const unsigned short* __restrict__ ch_g,
    const unsigned short* __restrict__ cl_g,
    const float*          __restrict__ h_g,
    float*                __restrict__ out) {
    __shared__ __align__(16) char lds[2 * 16384 + 2 * 256];
    const int tid  = threadIdx.x;
    const int lane = tid & 63;
    const int wid  = tid >> 6;
    const int col  = lane & 15;
    const int grp  = lane >> 4;
    const int tbase = blockIdx.x * 256 + wid * 32;

    bf16x8 zh[2][2], zl[2][2];
#pragma unroll
    for (int tt = 0; tt < 2; ++tt)
#pragma unroll
        for (int s = 0; s < 2; ++s) {
            const float* zp = ze + (size_t)(tbase + tt * 16 + col) * 64 + s * 32 + grp * 8;
            float4 v0 = *(const float4*)(zp);
            float4 v1 = *(const float4*)(zp + 4);
            float zv[8] = {v0.x, v0.y, v0.z, v0.w, v1.x, v1.y, v1.z, v1.w};
            bf16x8 hfr, lfr;
#pragma unroll
            for (int j = 0; j < 8; ++j) {
                unsigned short hb = f2bf_rne(zv[j]);
                unsigned short lb = f2bf_rne(zv[j] - bf2f(hb));
                hfr[j] = (short)hb;
                lfr[j] = (short)lb;
            }
            zh[tt][s] = hfr;
            zl[tt][s] = lfr;
        }

    float m1[2] = {INFINITY, INFINITY}, m2[2] = {INFINITY, INFINITY};
    int   ki[2] = {0, 0};

#define STAGE(cc, b)                                                            \
    do {                                                                        \
        int i = tid;                                                            \
        int4 va = *(const int4*)((const char*)ch_g + (cc) * 8192 + i * 16);     \
        int4 vb = *(const int4*)((const char*)cl_g + (cc) * 8192 + i * 16);     \
        int r = i >> 3, slot = i & 7;                                           \
        int st = r >> 4, row = r & 15;                                          \
        int off = (b) * 16384 + st * 2048 + row * 128 + ((slot ^ (row & 7)) << 4); \
        *(int4*)(lds + off) = va;                                               \
        *(int4*)(lds + off + 8192) = vb;                                        \
        if (i < 64) *(float*)(lds + 32768 + (b) * 256 + i * 4) = h_g[(cc) * 64 + i]; \
    } while (0)

    STAGE(0, 0);
    __syncthreads();

    for (int cc = 0; cc < 16; ++cc) {
        int b = cc & 1;
        if (cc + 1 < 16) STAGE(cc + 1, b ^ 1);

        for (int ct = 0; ct < 4; ++ct) {
            const int arow = b * 16384 + ct * 2048 + col * 128;
            bf16x8 ach0 = *(const bf16x8*)(lds + arow + ((((0 * 4) + grp) ^ (col & 7)) << 4));
            bf16x8 ach1 = *(const bf16x8*)(lds + arow + ((((1 * 4) + grp) ^ (col & 7)) << 4));
            bf16x8 acl0 = *(const bf16x8*)(lds + arow + 8192 + ((((0 * 4) + grp) ^ (col & 7)) << 4));
            bf16x8 acl1 = *(const bf16x8*)(lds + arow + 8192 + ((((1 * 4) + grp) ^ (col & 7)) << 4));
            f32x4 hv = *(const f32x4*)(lds + 32768 + b * 256 + ct * 64 + grp * 16);

            f32x4 acc0 = hv, acc1 = hv;
            acc0 = __builtin_amdgcn_mfma_f32_16x16x32_bf16(ach0, zh[0][0], acc0, 0, 0, 0);
            acc1 = __builtin_amdgcn_mfma_f32_16x16x32_bf16(ach0, zh[1][0], acc1, 0, 0, 0);
            acc0 = __builtin_amdgcn_mfma_f32_16x16x32_bf16(ach1, zh[0][1], acc0, 0, 0, 0);
            acc1 = __builtin_amdgcn_mfma_f32_16x16x32_bf16(ach1, zh[1][1], acc1, 0, 0, 0);
            acc0 = __builtin_amdgcn_mfma_f32_16x16x32_bf16(ach0, zl[0][0], acc0, 0, 0, 0);
            acc1 = __builtin_amdgcn_mfma_f32_16x16x32_bf16(ach0, zl[1][0], acc1, 0, 0, 0);
            acc0 = __builtin_amdgcn_mfma_f32_16x16x32_bf16(ach1, zl[0][1], acc0, 0, 0, 0);
            acc1 = __builtin_amdgcn_mfma_f32_16x16x32_bf16(ach1, zl[1][1], acc1, 0, 0, 0);
            acc0 = __builtin_amdgcn_mfma_f32_16x16x32_bf16(acl0, zh[0][0], acc0, 0, 0, 0);
            acc1 = __builtin_amdgcn_mfma_f32_16x16x32_bf16(acl0, zh[1][0], acc1, 0, 0, 0);
            acc0 = __builtin_amdgcn_mfma_f32_16x16x32_bf16(acl1, zh[0][1], acc0, 0, 0, 0);
            acc1 = __builtin_amdgcn_mfma_f32_16x16x32_bf16(acl1, zh[1][1], acc1, 0, 0, 0);

            const int kb = cc * 64 + ct * 16 + grp * 4;
#pragma unroll
            for (int j = 0; j < 4; ++j) {
                float s0 = acc0[j], s1 = acc1[j];
                bool lt0 = s0 < m1[0], lt1 = s1 < m1[1];
                m2[0] = fminf(m2[0], fmaxf(s0, m1[0]));
                m2[1] = fminf(m2[1], fmaxf(s1, m1[1]));
                ki[0] = lt0 ? (kb + j) : ki[0];
                ki[1] = lt1 ? (kb + j) : ki[1];
                m1[0] = fminf(m1[0], s0);
                m1[1] = fminf(m1[1], s1);
            }
        }
        __syncthreads();
    }

#pragma unroll
    for (int d = 16; d <= 32; d <<= 1) {
#pragma unroll
        for (int tt = 0; tt < 2; ++tt) {
            float om1 = __shfl_xor(m1[tt], d, 64);
            float om2 = __shfl_xor(m2[tt], d, 64);
            int   oki = __shfl_xor(ki[tt], d, 64);
            m2[tt] = fminf(fminf(m2[tt], om2), fmaxf(m1[tt], om1));
            ki[tt] = (om1 < m1[tt]) ? oki : ki[tt];
            m1[tt] = fminf(m1[tt], om1);
        }
    }
    if (lane < 16) {
#pragma unroll
        for (int tt = 0; tt < 2; ++tt) {
            int t = tbase + tt * 16 + lane;
            bool flag = (m2[tt] - m1[tt]) < EPS_FLAG;
            out[OUT_IDX + t] = flag ? -(float)(ki[tt] + 1) : (float)ki[tt];
        }
    }
}

// Kernel 2: FINISH -- per block: own 512 tokens; ballot flagged; stage fp32
// codebook half-by-half in LDS (r10-proven layout); rescue own flagged tokens
// (frozen formula, u64 key min); gather unflagged rows FROM LDS, flagged from
// global; SSE once from final idx; wave-wide histogram atomic; last-block
// finalize.
__global__ __launch_bounds__(512) void vq_finish(
    const float* __restrict__ ze, const float* __restrict__ cb,
    const float* __restrict__ h_g, float* __restrict__ out,
    double* __restrict__ sse_g, int* __restrict__ counts,
    int* __restrict__ done) {
    __shared__ __align__(16) float4 cbl[512 * 17];           // 139,264 B
    __shared__ float zst[8][64];
    __shared__ unsigned long long keys[8][64];
    __shared__ float hl[NEMB];
    __shared__ double red[8];
    __shared__ int flagS;
    const int tid  = threadIdx.x;
    const int lane = tid & 63;
    const int wid  = tid >> 6;
    const int wbase = blockIdx.x * 512 + wid * 64;

    for (int i = tid; i < NEMB; i += 512) hl[i] = h_g[i];

    // per-lane token record: lane l owns token wbase+l
    float fidx = out[OUT_IDX + wbase + lane];
    bool myflag = fidx < 0.0f;
    int  myk = myflag ? ((int)(-fidx) - 1) : (int)fidx;
    const unsigned long long fmask = __ballot(myflag);

    double lsse = 0.0;
    const float4* cb4 = (const float4*)cb;

    for (int hf = 0; hf < 2; ++hf) {
        __syncthreads();
#pragma unroll
        for (int j = 0; j < 16; ++j) {
            int f = tid + j * 512;
            int code = f >> 4, d4 = f & 15;
            cbl[code * 17 + d4] = cb4[(size_t)(hf * 512 + code) * 16 + d4];
        }
        __syncthreads();

        // --- rescue scans for this wave's flagged tokens (frozen math) ---
        unsigned long long m = fmask;
        while (m) {
            const int b = __builtin_ctzll(m);
            m &= m - 1;
            const int t = wbase + b;

            zst[wid][lane] = ze[(size_t)t * 64 + lane];
            __builtin_amdgcn_wave_barrier();
            asm volatile("s_waitcnt lgkmcnt(0)" ::: "memory");
            __builtin_amdgcn_sched_barrier(0);

            float sz;
#define GZ(d) (zst[wid][d])
            NP_PAIRWISE_SQ64(GZ, sz);
#undef GZ

            float acc[8] = {0.f, 0.f, 0.f, 0.f, 0.f, 0.f, 0.f, 0.f};
            const float4* zr4 = (const float4*)zst[wid];
#pragma unroll
            for (int d4 = 0; d4 < 16; ++d4) {
                float4 zq = zr4[d4];
#pragma unroll
                for (int cc = 0; cc < 8; ++cc) {
                    float4 cv = cbl[(lane + 64 * cc) * 17 + d4];
                    acc[cc] = fmaf(cv.x, zq.x, acc[cc]);
                    acc[cc] = fmaf(cv.y, zq.y, acc[cc]);
                    acc[cc] = fmaf(cv.z, zq.z, acc[cc]);
                    acc[cc] = fmaf(cv.w, zq.w, acc[cc]);
                }
            }
            unsigned long long key = ~0ull;
#pragma unroll
            for (int cc = 0; cc < 8; ++cc) {
                unsigned k = (unsigned)(hf * 512 + lane + 64 * cc);
                float dk = (sz + hl[k]) - 2.0f * acc[cc];   // frozen np formula
                unsigned long long c =
                    ((unsigned long long)__float_as_uint(dk) << 32) | k;
                key = c < key ? c : key;
            }
#pragma unroll
            for (int dd = 1; dd < 64; dd <<= 1) {
                unsigned long long o = __shfl_xor(key, dd, 64);
                key = o < key ? o : key;
            }
            if (hf == 0) {
                if (lane == 0) keys[wid][b] = key;
            } else {
                unsigned long long k0 = keys[wid][b];   // wave-local broadcast
                if (k0 < key) key = k0;
                int newk = (int)(unsigned)(key & 0xFFFFFFFFull);
                if (lane == b) myk = newk;              // lane b owns token b
            }
        }

        // --- gather unflagged tokens whose code lives in this half (from LDS) ---
        const float* cblf = (const float*)cbl;
        for (int tok = 0; tok < 64; ++tok) {
            if ((fmask >> tok) & 1ull) continue;
            int k = __shfl(myk, tok, 64);
            if (k < hf * 512 || k >= hf * 512 + 512) continue;
            int t = wbase + tok;
            float q  = cblf[(k - hf * 512) * 68 + lane];   // 17 float4 = 68 floats/row
            float zv = ze[(size_t)t * 64 + lane];
            out[(size_t)t * 64 + lane] = q;
            double diff = (double)q - (double)zv;
            lsse = fma(diff, diff, lsse);
        }
    }

    // --- flagged tokens: gather from global cb with FINAL idx ---
    {
        unsigned long long m = fmask;
        while (m) {
            const int b = __builtin_ctzll(m);
            m &= m - 1;
            int k = __shfl(myk, b, 64);
            int t = wbase + b;
            float q  = cb[k * 64 + lane];
            float zv = ze[(size_t)t * 64 + lane];
            out[(size_t)t * 64 + lane] = q;
            double diff = (double)q - (double)zv;
            lsse = fma(diff, diff, lsse);
        }
    }

    // idx rewrite (clears flags; coalesced) + histogram (wave-wide atomic)
    out[OUT_IDX + wbase + lane] = (float)myk;
    atomicAdd(&counts[myk], 1);

    // SSE: wave reduce -> block reduce -> one atomic
#pragma unroll
    for (int off = 32; off > 0; off >>= 1)
        lsse += __shfl_down(lsse, off, 64);
    if (lane == 0) red[wid] = lsse;
    __syncthreads();
    if (tid == 0) {
        double bs = ((red[0] + red[1]) + (red[2] + red[3]))
                  + ((red[4] + red[5]) + (red[6] + red[7]));
        atomicAdd(sse_g, bs);
        __threadfence();
        flagS = (atomicAdd(done, 1) == 255);
    }
    __syncthreads();

    // last block finalizes loss + perplexity
    if (flagS) {
        __threadfence();
        double* red2 = (double*)cbl;   // staging LDS dead here
        double local = 0.0;
        for (int k = tid; k < NEMB; k += 512) {
            int cv = __hip_atomic_load(&counts[k], __ATOMIC_RELAXED, __HIP_MEMORY_SCOPE_AGENT);
            double p = (double)cv / (double)NTOK;
            local += p * log(p + 1e-10);
        }
        red2[tid] = local;
        __syncthreads();
        for (int s = 256; s > 0; s >>= 1) {
            if (tid < s) red2[tid] += red2[tid + s];
            __syncthreads();
        }
        if (tid == 0) {
            double sv = __hip_atomic_load(sse_g, __ATOMIC_RELAXED, __HIP_MEMORY_SCOPE_AGENT);
            double mse = sv / ((double)NTOK * (double)DIM);
            out[OUT_LOSS] = (float)(1.25 * mse);
            out[OUT_PERP] = (float)exp(-red2[0]);
        }
    }
}

extern "C" void kernel_launch(void* const* d_in, const int* in_sizes, int n_in,
                              void* d_out, int out_size, void* d_ws, size_t ws_size,
                              hipStream_t stream) {
    const float* ze = (const float*)d_in[0];
    const float* cb = (const float*)d_in[1];
    float* out = (float*)d_out;

    char* w = (char*)d_ws;
    double*         sse    = (double*)w;                    // @0
    int*            counts = (int*)(w + 64);                // @64   (4 KiB)
    int*            done   = (int*)(w + 4160);              // @4160
    float*          h      = (float*)(w + 4224);            // @4224 (4 KiB)
    unsigned short* ch     = (unsigned short*)(w + 8320);   // 128 KiB
    unsigned short* cl     = (unsigned short*)(w + 139392); // 128 KiB

    vq_prep<<<NEMB / 256, 256, 0, stream>>>(cb, h, ch, cl, sse, counts, done);
    vq_screen<<<NTOK / 256, 512, 0, stream>>>(ze, ch, cl, h, out);
    vq_finish<<<NTOK / 512, 512, 0, stream>>>(ze, cb, h, out, sse, counts, done);
}

// Round 14
// 168.699 us; speedup vs baseline: 1.5884x; 1.1253x over previous
//
#include <hip/hip_runtime.h>
#include <math.h>

// VectorQuantizer: N=131072 tokens, K=1024 codes, D=64, fp32.
// Out layout (flat): z_q_st[N*D] | loss | perplexity | indices[N] (as f32)
#define NTOK 131072
#define NEMB 1024
#define DIM  64
#define OUT_LOSS (NTOK * DIM)
#define OUT_PERP (OUT_LOSS + 1)
#define OUT_IDX  (OUT_LOSS + 2)

#define EPS_FLAG 6e-5f   // screen ambiguity margin (frozen; passed r3-r13)

typedef short bf16x8 __attribute__((ext_vector_type(8)));
typedef float f32x4  __attribute__((ext_vector_type(4)));

// ---- numpy fp32 semantics helpers (frozen from round 2 -- PASSED) ----------
__device__ __forceinline__ float sqb(float x) {
    float y = x * x;
    asm volatile("" : "+v"(y));
    return y;
}
// numpy pairwise_sum for n=64 contiguous: 8 accumulators stride 8, then
// ((r0+r1)+(r2+r3))+((r4+r5)+(r6+r7)).
#define NP_PAIRWISE_SQ64(GET, RES)                                     \
    do {                                                               \
        float r0 = sqb(GET(0)), r1 = sqb(GET(1)), r2 = sqb(GET(2)),    \
              r3 = sqb(GET(3)), r4 = sqb(GET(4)), r5 = sqb(GET(5)),    \
              r6 = sqb(GET(6)), r7 = sqb(GET(7));                      \
        _Pragma("unroll")                                              \
        for (int i = 8; i < 64; i += 8) {                              \
            r0 += sqb(GET(i + 0)); r1 += sqb(GET(i + 1));              \
            r2 += sqb(GET(i + 2)); r3 += sqb(GET(i + 3));              \
            r4 += sqb(GET(i + 4)); r5 += sqb(GET(i + 5));              \
            r6 += sqb(GET(i + 6)); r7 += sqb(GET(i + 7));              \
        }                                                              \
        RES = ((r0 + r1) + (r2 + r3)) + ((r4 + r5) + (r6 + r7));       \
    } while (0)

__device__ __forceinline__ unsigned short f2bf_rne(float x) {
    unsigned u = __float_as_uint(x);
    u += 0x7FFFu + ((u >> 16) & 1u);   // round-to-nearest-even
    return (unsigned short)(u >> 16);
}
__device__ __forceinline__ float bf2f(unsigned short b) {
    return __uint_as_float(((unsigned)b) << 16);
}

// ws layout (bytes):
//   0:      sse double
//   64:     counts int[1024]
//   4160:   qcount int
//   4168:   done int
//   4224:   h float[1024]
//   8320:   ch bf16[1024*64]   (128 KiB)
//   139392: cl bf16[1024*64]   (128 KiB)
//   270464: qlist int[NTOK]    (512 KiB)

// Kernel 0: h[k] np-exact; ch/cl bf16 split of (-2c); block 0 zeroes accums.
__global__ void vq_prep(const float* __restrict__ cb, float* __restrict__ h,
                        unsigned short* __restrict__ ch, unsigned short* __restrict__ cl,
                        double* __restrict__ sse, int* __restrict__ counts,
                        int* __restrict__ qcount, int* __restrict__ done) {
    if (blockIdx.x == 0) {
        if (threadIdx.x == 0) { *sse = 0.0; *qcount = 0; *done = 0; }
        for (int i = threadIdx.x; i < NEMB; i += 256) counts[i] = 0;
    }
    int k = blockIdx.x * 256 + threadIdx.x;
    if (k >= NEMB) return;
    float c[64];
    const float4* p = (const float4*)(cb + k * DIM);
#pragma unroll
    for (int q = 0; q < 16; ++q) {
        float4 v = p[q];
        c[4 * q] = v.x; c[4 * q + 1] = v.y; c[4 * q + 2] = v.z; c[4 * q + 3] = v.w;
    }
    float hk;
#define GETC(d) (c[d])
    NP_PAIRWISE_SQ64(GETC, hk);
#undef GETC
    h[k] = hk;
#pragma unroll
    for (int b = 0; b < 8; ++b) {
        unsigned uhv[4], ulv[4];
#pragma unroll
        for (int e = 0; e < 4; ++e) {
            float x0 = -2.0f * c[b * 8 + e * 2 + 0];
            float x1 = -2.0f * c[b * 8 + e * 2 + 1];
            unsigned short h0 = f2bf_rne(x0), h1 = f2bf_rne(x1);
            unsigned short l0 = f2bf_rne(x0 - bf2f(h0)), l1 = f2bf_rne(x1 - bf2f(h1));
            uhv[e] = (unsigned)h0 | ((unsigned)h1 << 16);
            ulv[e] = (unsigned)l0 | ((unsigned)l1 << 16);
        }
        *(uint4*)(ch + k * 64 + b * 8) = make_uint4(uhv[0], uhv[1], uhv[2], uhv[3]);
        *(uint4*)(cl + k * 64 + b * 8) = make_uint4(ulv[0], ulv[1], ulv[2], ulv[3]);
    }
}

// Kernel 1: MFMA screen -- r13 VERBATIM (fastest measured ~50us).
// Ambiguity flag in the SIGN of the idx float; no atomics, no epilogue.
__global__ __launch_bounds__(512) void vq_screen(
    const float*          __restrict__ ze,
    const unsigned short* __restrict__ ch_g,
    const unsigned short* __restrict__ cl_g,
    const float*          __restrict__ h_g,
    float*                __restrict__ out) {
    __shared__ __align__(16) char lds[2 * 16384 + 2 * 256];
    const int tid  = threadIdx.x;
    const int lane = tid & 63;
    const int wid  = tid >> 6;
    const int col  = lane & 15;
    const int grp  = lane >> 4;
    const int tbase = blockIdx.x * 256 + wid * 32;

    bf16x8 zh[2][2], zl[2][2];
#pragma unroll
    for (int tt = 0; tt < 2; ++tt)
#pragma unroll
        for (int s = 0; s < 2; ++s) {
            const float* zp = ze + (size_t)(tbase + tt * 16 + col) * 64 + s * 32 + grp * 8;
            float4 v0 = *(const float4*)(zp);
            float4 v1 = *(const float4*)(zp + 4);
            float zv[8] = {v0.x, v0.y, v0.z, v0.w, v1.x, v1.y, v1.z, v1.w};
            bf16x8 hfr, lfr;
#pragma unroll
            for (int j = 0; j < 8; ++j) {
                unsigned short hb = f2bf_rne(zv[j]);
                unsigned short lb = f2bf_rne(zv[j] - bf2f(hb));
                hfr[j] = (short)hb;
                lfr[j] = (short)lb;
            }
            zh[tt][s] = hfr;
            zl[tt][s] = lfr;
        }

    float m1[2] = {INFINITY, INFINITY}, m2[2] = {INFINITY, INFINITY};
    int   ki[2] = {0, 0};

#define STAGE(cc, b)                                                            \
    do {                                                                        \
        int i = tid;                                                            \
        int4 va = *(const int4*)((const char*)ch_g + (cc) * 8192 + i * 16);     \
        int4 vb = *(const int4*)((const char*)cl_g + (cc) * 8192 + i * 16);     \
        int r = i >> 3, slot = i & 7;                                           \
        int st = r >> 4, row = r & 15;                                          \
        int off = (b) * 16384 + st * 2048 + row * 128 + ((slot ^ (row & 7)) << 4); \
        *(int4*)(lds + off) = va;                                               \
        *(int4*)(lds + off + 8192) = vb;                                        \
        if (i < 64) *(float*)(lds + 32768 + (b) * 256 + i * 4) = h_g[(cc) * 64 + i]; \
    } while (0)

    STAGE(0, 0);
    __syncthreads();

    for (int cc = 0; cc < 16; ++cc) {
        int b = cc & 1;
        if (cc + 1 < 16) STAGE(cc + 1, b ^ 1);

        for (int ct = 0; ct < 4; ++ct) {
            const int arow = b * 16384 + ct * 2048 + col * 128;
            bf16x8 ach0 = *(const bf16x8*)(lds + arow + ((((0 * 4) + grp) ^ (col & 7)) << 4));
            bf16x8 ach1 = *(const bf16x8*)(lds + arow + ((((1 * 4) + grp) ^ (col & 7)) << 4));
            bf16x8 acl0 = *(const bf16x8*)(lds + arow + 8192 + ((((0 * 4) + grp) ^ (col & 7)) << 4));
            bf16x8 acl1 = *(const bf16x8*)(lds + arow + 8192 + ((((1 * 4) + grp) ^ (col & 7)) << 4));
            f32x4 hv = *(const f32x4*)(lds + 32768 + b * 256 + ct * 64 + grp * 16);

            f32x4 acc0 = hv, acc1 = hv;
            acc0 = __builtin_amdgcn_mfma_f32_16x16x32_bf16(ach0, zh[0][0], acc0, 0, 0, 0);
            acc1 = __builtin_amdgcn_mfma_f32_16x16x32_bf16(ach0, zh[1][0], acc1, 0, 0, 0);
            acc0 = __builtin_amdgcn_mfma_f32_16x16x32_bf16(ach1, zh[0][1], acc0, 0, 0, 0);
            acc1 = __builtin_amdgcn_mfma_f32_16x16x32_bf16(ach1, zh[1][1], acc1, 0, 0, 0);
            acc0 = __builtin_amdgcn_mfma_f32_16x16x32_bf16(ach0, zl[0][0], acc0, 0, 0, 0);
            acc1 = __builtin_amdgcn_mfma_f32_16x16x32_bf16(ach0, zl[1][0], acc1, 0, 0, 0);
            acc0 = __builtin_amdgcn_mfma_f32_16x16x32_bf16(ach1, zl[0][1], acc0, 0, 0, 0);
            acc1 = __builtin_amdgcn_mfma_f32_16x16x32_bf16(ach1, zl[1][1], acc1, 0, 0, 0);
            acc0 = __builtin_amdgcn_mfma_f32_16x16x32_bf16(acl0, zh[0][0], acc0, 0, 0, 0);
            acc1 = __builtin_amdgcn_mfma_f32_16x16x32_bf16(acl0, zh[1][0], acc1, 0, 0, 0);
            acc0 = __builtin_amdgcn_mfma_f32_16x16x32_bf16(acl1, zh[0][1], acc0, 0, 0, 0);
            acc1 = __builtin_amdgcn_mfma_f32_16x16x32_bf16(acl1, zh[1][1], acc1, 0, 0, 0);

            const int kb = cc * 64 + ct * 16 + grp * 4;
#pragma unroll
            for (int j = 0; j < 4; ++j) {
                float s0 = acc0[j], s1 = acc1[j];
                bool lt0 = s0 < m1[0], lt1 = s1 < m1[1];
                m2[0] = fminf(m2[0], fmaxf(s0, m1[0]));
                m2[1] = fminf(m2[1], fmaxf(s1, m1[1]));
                ki[0] = lt0 ? (kb + j) : ki[0];
                ki[1] = lt1 ? (kb + j) : ki[1];
                m1[0] = fminf(m1[0], s0);
                m1[1] = fminf(m1[1], s1);
            }
        }
        __syncthreads();
    }

#pragma unroll
    for (int d = 16; d <= 32; d <<= 1) {
#pragma unroll
        for (int tt = 0; tt < 2; ++tt) {
            float om1 = __shfl_xor(m1[tt], d, 64);
            float om2 = __shfl_xor(m2[tt], d, 64);
            int   oki = __shfl_xor(ki[tt], d, 64);
            m2[tt] = fminf(fminf(m2[tt], om2), fmaxf(m1[tt], om1));
            ki[tt] = (om1 < m1[tt]) ? oki : ki[tt];
            m1[tt] = fminf(m1[tt], om1);
        }
    }
    if (lane < 16) {
#pragma unroll
        for (int tt = 0; tt < 2; ++tt) {
            int t = tbase + tt * 16 + lane;
            bool flag = (m2[tt] - m1[tt]) < EPS_FLAG;
            out[OUT_IDX + t] = flag ? -(float)(ki[tt] + 1) : (float)ki[tt];
        }
    }
}

// Kernel 2: streaming gather (r8's proven 2048x256 structure). Unflagged:
// gather/SSE/histogram. Flagged: skip + append to qlist (cheap, distributed).
__global__ __launch_bounds__(256) void vq_gather(
    const float* __restrict__ ze, const float* __restrict__ cb,
    float* __restrict__ out, double* __restrict__ sse_g, int* __restrict__ counts,
    int* __restrict__ qcount, int* __restrict__ qlist) {
    const int base = blockIdx.x * 256 + threadIdx.x;
    const int stride = 2048 * 256;
    double lsse = 0.0;
#pragma unroll
    for (int it = 0; it < 16; ++it) {
        int gid = base + it * stride;
        int n = gid >> 6, d = gid & 63;
        float fidx = out[OUT_IDX + n];
        if (fidx < 0.0f) {
            if (d == 0) { int slot = atomicAdd(qcount, 1); qlist[slot] = n; }
            continue;
        }
        int idx = (int)fidx;
        float q = cb[idx * DIM + d];
        float zv = ze[gid];
        out[gid] = q;
        if (d == 0) atomicAdd(&counts[idx], 1);
        double diff = (double)q - (double)zv;
        lsse = fma(diff, diff, lsse);
    }
#pragma unroll
    for (int off = 32; off > 0; off >>= 1)
        lsse += __shfl_down(lsse, off, 64);
    __shared__ double red[4];
    if ((threadIdx.x & 63) == 0) red[threadIdx.x >> 6] = lsse;
    __syncthreads();
    if (threadIdx.x == 0)
        atomicAdd(sse_g, (red[0] + red[1]) + (red[2] + red[3]));
}

// Kernel 3: rescue (r8's proven LDS-staged scan, 256 blocks) -- owns queued
// tokens end-to-end: final idx, row write, SSE, histogram. Last-block finalize.
__global__ __launch_bounds__(512) void vq_rescue(
    const float* __restrict__ ze, const float* __restrict__ cb,
    const float* __restrict__ h_g, const int* __restrict__ qcount,
    const int* __restrict__ qlist, float* __restrict__ out,
    double* __restrict__ sse_g, int* __restrict__ counts,
    int* __restrict__ done) {
    __shared__ __align__(16) float4 cbl[512 * 17];          // 139,264 B
    __shared__ float zst[8][64];
    __shared__ unsigned long long keys[8][64];
    __shared__ float hl[NEMB];
    __shared__ double red[8];
    __shared__ int flagS;
    const int tid  = threadIdx.x;
    const int lane = tid & 63;
    const int wid  = tid >> 6;
    const int nq   = *qcount;
    const int per  = (nq + 255) >> 8;
    const int i0   = blockIdx.x * per;
    const int iend = (i0 + per < nq) ? (i0 + per) : nq;
    double lsse = 0.0;

    if (i0 < iend) {   // block-uniform
        for (int i = tid; i < NEMB; i += 512) hl[i] = h_g[i];
        const float4* cb4 = (const float4*)cb;

        for (int hf = 0; hf < 2; ++hf) {
            __syncthreads();
#pragma unroll
            for (int j = 0; j < 16; ++j) {
                int f = tid + j * 512;
                int code = f >> 4, d4 = f & 15;
                cbl[code * 17 + d4] = cb4[(size_t)(hf * 512 + code) * 16 + d4];
            }
            __syncthreads();

            for (int i = i0 + wid; i < iend; i += 8) {
                const int t = qlist[i];
                const int slot = (i - i0) >> 3;

                zst[wid][lane] = ze[(size_t)t * 64 + lane];
                __builtin_amdgcn_wave_barrier();
                asm volatile("s_waitcnt lgkmcnt(0)" ::: "memory");
                __builtin_amdgcn_sched_barrier(0);

                float sz;
#define GZ(d) (zst[wid][d])
                NP_PAIRWISE_SQ64(GZ, sz);
#undef GZ

                float acc[8] = {0.f, 0.f, 0.f, 0.f, 0.f, 0.f, 0.f, 0.f};
                const float4* zr4 = (const float4*)zst[wid];
#pragma unroll
                for (int d4 = 0; d4 < 16; ++d4) {
                    float4 zq = zr4[d4];
#pragma unroll
                    for (int cc = 0; cc < 8; ++cc) {
                        float4 cv = cbl[(lane + 64 * cc) * 17 + d4];
                        acc[cc] = fmaf(cv.x, zq.x, acc[cc]);
                        acc[cc] = fmaf(cv.y, zq.y, acc[cc]);
                        acc[cc] = fmaf(cv.z, zq.z, acc[cc]);
                        acc[cc] = fmaf(cv.w, zq.w, acc[cc]);
                    }
                }
                unsigned long long key = ~0ull;
#pragma unroll
                for (int cc = 0; cc < 8; ++cc) {
                    unsigned k = (unsigned)(hf * 512 + lane + 64 * cc);
                    float dk = (sz + hl[k]) - 2.0f * acc[cc];   // frozen formula
                    unsigned long long c =
                        ((unsigned long long)__float_as_uint(dk) << 32) | k;
                    key = c < key ? c : key;
                }
#pragma unroll
                for (int dd = 1; dd < 64; dd <<= 1) {
                    unsigned long long o = __shfl_xor(key, dd, 64);
                    key = o < key ? o : key;
                }
                if (hf == 0) {
                    if (lane == 0) keys[wid][slot] = key;
                } else {
                    unsigned long long k0 = keys[wid][slot];  // LDS broadcast
                    if (k0 < key) key = k0;
                    int newk = (int)(unsigned)(key & 0xFFFFFFFFull);
                    // own this token end-to-end
                    float q  = cb[newk * 64 + lane];
                    float zv = zst[wid][lane];
                    out[(size_t)t * 64 + lane] = q;
                    double diff = (double)q - (double)zv;
                    lsse = fma(diff, diff, lsse);
                    if (lane == 0) {
                        out[OUT_IDX + t] = (float)newk;
                        atomicAdd(&counts[newk], 1);
                    }
                }
            }
        }
    }

    // SSE contribution (blocks with work), then all blocks hit done-counter
#pragma unroll
    for (int off = 32; off > 0; off >>= 1)
        lsse += __shfl_down(lsse, off, 64);
    if (lane == 0) red[wid] = lsse;
    __syncthreads();
    if (tid == 0) {
        double bs = ((red[0] + red[1]) + (red[2] + red[3]))
                  + ((red[4] + red[5]) + (red[6] + red[7]));
        if (bs != 0.0) atomicAdd(sse_g, bs);
        __threadfence();
        flagS = (atomicAdd(done, 1) == 255);
    }
    __syncthreads();

    // last block finalizes loss + perplexity
    if (flagS) {
        __threadfence();
        double* red2 = (double*)cbl;   // staging LDS dead here
        double local = 0.0;
        for (int k = tid; k < NEMB; k += 512) {
            int cv = __hip_atomic_load(&counts[k], __ATOMIC_RELAXED, __HIP_MEMORY_SCOPE_AGENT);
            double p = (double)cv / (double)NTOK;
            local += p * log(p + 1e-10);
        }
        red2[tid] = local;
        __syncthreads();
        for (int s = 256; s > 0; s >>= 1) {
            if (tid < s) red2[tid] += red2[tid + s];
            __syncthreads();
        }
        if (tid == 0) {
            double sv = __hip_atomic_load(sse_g, __ATOMIC_RELAXED, __HIP_MEMORY_SCOPE_AGENT);
            double mse = sv / ((double)NTOK * (double)DIM);
            out[OUT_LOSS] = (float)(1.25 * mse);
            out[OUT_PERP] = (float)exp(-red2[0]);
        }
    }
}

extern "C" void kernel_launch(void* const* d_in, const int* in_sizes, int n_in,
                              void* d_out, int out_size, void* d_ws, size_t ws_size,
                              hipStream_t stream) {
    const float* ze = (const float*)d_in[0];
    const float* cb = (const float*)d_in[1];
    float* out = (float*)d_out;

    char* w = (char*)d_ws;
    double*         sse    = (double*)w;                    // @0
    int*            counts = (int*)(w + 64);                // @64   (4 KiB)
    int*            qcount = (int*)(w + 4160);              // @4160
    int*            done   = (int*)(w + 4168);              // @4168
    float*          h      = (float*)(w + 4224);            // @4224 (4 KiB)
    unsigned short* ch     = (unsigned short*)(w + 8320);   // 128 KiB
    unsigned short* cl     = (unsigned short*)(w + 139392); // 128 KiB
    int*            qlist  = (int*)(w + 270464);            // 512 KiB

    vq_prep<<<NEMB / 256, 256, 0, stream>>>(cb, h, ch, cl, sse, counts, qcount, done);
    vq_screen<<<NTOK / 256, 512, 0, stream>>>(ze, ch, cl, h, out);
    vq_gather<<<2048, 256, 0, stream>>>(ze, cb, out, sse, counts, qcount, qlist);
    vq_rescue<<<256, 512, 0, stream>>>(ze, cb, h, qcount, qlist, out, sse, counts, done);
}

// Round 15
// 161.986 us; speedup vs baseline: 1.6542x; 1.0414x over previous
//
#include <hip/hip_runtime.h>
#include <math.h>

// VectorQuantizer: N=131072 tokens, K=1024 codes, D=64, fp32.
// Out layout (flat): z_q_st[N*D] | loss | perplexity | indices[N] (as f32)
#define NTOK 131072
#define NEMB 1024
#define DIM  64
#define OUT_LOSS (NTOK * DIM)
#define OUT_PERP (OUT_LOSS + 1)
#define OUT_IDX  (OUT_LOSS + 2)

#define EPS_FLAG 6e-5f   // screen ambiguity margin (frozen; passed r3-r14)

typedef short bf16x8 __attribute__((ext_vector_type(8)));
typedef float f32x4  __attribute__((ext_vector_type(4)));

// ---- numpy fp32 semantics helpers (frozen from round 2 -- PASSED) ----------
__device__ __forceinline__ float sqb(float x) {
    float y = x * x;
    asm volatile("" : "+v"(y));
    return y;
}
// numpy pairwise_sum for n=64 contiguous: 8 accumulators stride 8, then
// ((r0+r1)+(r2+r3))+((r4+r5)+(r6+r7)).
#define NP_PAIRWISE_SQ64(GET, RES)                                     \
    do {                                                               \
        float r0 = sqb(GET(0)), r1 = sqb(GET(1)), r2 = sqb(GET(2)),    \
              r3 = sqb(GET(3)), r4 = sqb(GET(4)), r5 = sqb(GET(5)),    \
              r6 = sqb(GET(6)), r7 = sqb(GET(7));                      \
        _Pragma("unroll")                                              \
        for (int i = 8; i < 64; i += 8) {                              \
            r0 += sqb(GET(i + 0)); r1 += sqb(GET(i + 1));              \
            r2 += sqb(GET(i + 2)); r3 += sqb(GET(i + 3));              \
            r4 += sqb(GET(i + 4)); r5 += sqb(GET(i + 5));              \
            r6 += sqb(GET(i + 6)); r7 += sqb(GET(i + 7));              \
        }                                                              \
        RES = ((r0 + r1) + (r2 + r3)) + ((r4 + r5) + (r6 + r7));       \
    } while (0)

__device__ __forceinline__ unsigned short f2bf_rne(float x) {
    unsigned u = __float_as_uint(x);
    u += 0x7FFFu + ((u >> 16) & 1u);   // round-to-nearest-even
    return (unsigned short)(u >> 16);
}
__device__ __forceinline__ float bf2f(unsigned short b) {
    return __uint_as_float(((unsigned)b) << 16);
}

// ws layout (bytes):
//   0:      sse double
//   64:     counts int[1024*16]  (64 KiB, one counter per 64B line)
//   65600:  qcount int
//   65608:  done int
//   65664:  h float[1024]        (4 KiB)
//   69760:  ch bf16[1024*64]     (128 KiB)
//   200832: cl bf16[1024*64]     (128 KiB)
//   331904: qlist int[NTOK]      (512 KiB)

// Kernel 0: h[k] np-exact; ch/cl bf16 split of (-2c); block 0 zeroes accums.
__global__ void vq_prep(const float* __restrict__ cb, float* __restrict__ h,
                        unsigned short* __restrict__ ch, unsigned short* __restrict__ cl,
                        double* __restrict__ sse, int* __restrict__ counts,
                        int* __restrict__ qcount, int* __restrict__ done) {
    if (blockIdx.x == 0) {
        if (threadIdx.x == 0) { *sse = 0.0; *qcount = 0; *done = 0; }
        for (int i = threadIdx.x; i < NEMB * 16; i += 256) counts[i] = 0;
    }
    int k = blockIdx.x * 256 + threadIdx.x;
    if (k >= NEMB) return;
    float c[64];
    const float4* p = (const float4*)(cb + k * DIM);
#pragma unroll
    for (int q = 0; q < 16; ++q) {
        float4 v = p[q];
        c[4 * q] = v.x; c[4 * q + 1] = v.y; c[4 * q + 2] = v.z; c[4 * q + 3] = v.w;
    }
    float hk;
#define GETC(d) (c[d])
    NP_PAIRWISE_SQ64(GETC, hk);
#undef GETC
    h[k] = hk;
#pragma unroll
    for (int b = 0; b < 8; ++b) {
        unsigned uhv[4], ulv[4];
#pragma unroll
        for (int e = 0; e < 4; ++e) {
            float x0 = -2.0f * c[b * 8 + e * 2 + 0];
            float x1 = -2.0f * c[b * 8 + e * 2 + 1];
            unsigned short h0 = f2bf_rne(x0), h1 = f2bf_rne(x1);
            unsigned short l0 = f2bf_rne(x0 - bf2f(h0)), l1 = f2bf_rne(x1 - bf2f(h1));
            uhv[e] = (unsigned)h0 | ((unsigned)h1 << 16);
            ulv[e] = (unsigned)l0 | ((unsigned)l1 << 16);
        }
        *(uint4*)(ch + k * 64 + b * 8) = make_uint4(uhv[0], uhv[1], uhv[2], uhv[3]);
        *(uint4*)(cl + k * 64 + b * 8) = make_uint4(ulv[0], ulv[1], ulv[2], ulv[3]);
    }
}

// Kernel 1: MFMA screen -- r13/r14 VERBATIM (fastest measured ~62us).
// Ambiguity flag in the SIGN of the idx float; no atomics, no epilogue.
__global__ __launch_bounds__(512) void vq_screen(
    const float*          __restrict__ ze,
    const unsigned short* __restrict__ ch_g,
    const unsigned short* __restrict__ cl_g,
    const float*          __restrict__ h_g,
    float*                __restrict__ out) {
    __shared__ __align__(16) char lds[2 * 16384 + 2 * 256];
    const int tid  = threadIdx.x;
    const int lane = tid & 63;
    const int wid  = tid >> 6;
    const int col  = lane & 15;
    const int grp  = lane >> 4;
    const int tbase = blockIdx.x * 256 + wid * 32;

    bf16x8 zh[2][2], zl[2][2];
#pragma unroll
    for (int tt = 0; tt < 2; ++tt)
#pragma unroll
        for (int s = 0; s < 2; ++s) {
            const float* zp = ze + (size_t)(tbase + tt * 16 + col) * 64 + s * 32 + grp * 8;
            float4 v0 = *(const float4*)(zp);
            float4 v1 = *(const float4*)(zp + 4);
            float zv[8] = {v0.x, v0.y, v0.z, v0.w, v1.x, v1.y, v1.z, v1.w};
            bf16x8 hfr, lfr;
#pragma unroll
            for (int j = 0; j < 8; ++j) {
                unsigned short hb = f2bf_rne(zv[j]);
                unsigned short lb = f2bf_rne(zv[j] - bf2f(hb));
                hfr[j] = (short)hb;
                lfr[j] = (short)lb;
            }
            zh[tt][s] = hfr;
            zl[tt][s] = lfr;
        }

    float m1[2] = {INFINITY, INFINITY}, m2[2] = {INFINITY, INFINITY};
    int   ki[2] = {0, 0};

#define STAGE(cc, b)                                                            \
    do {                                                                        \
        int i = tid;                                                            \
        int4 va = *(const int4*)((const char*)ch_g + (cc) * 8192 + i * 16);     \
        int4 vb = *(const int4*)((const char*)cl_g + (cc) * 8192 + i * 16);     \
        int r = i >> 3, slot = i & 7;                                           \
        int st = r >> 4, row = r & 15;                                          \
        int off = (b) * 16384 + st * 2048 + row * 128 + ((slot ^ (row & 7)) << 4); \
        *(int4*)(lds + off) = va;                                               \
        *(int4*)(lds + off + 8192) = vb;                                        \
        if (i < 64) *(float*)(lds + 32768 + (b) * 256 + i * 4) = h_g[(cc) * 64 + i]; \
    } while (0)

    STAGE(0, 0);
    __syncthreads();

    for (int cc = 0; cc < 16; ++cc) {
        int b = cc & 1;
        if (cc + 1 < 16) STAGE(cc + 1, b ^ 1);

        for (int ct = 0; ct < 4; ++ct) {
            const int arow = b * 16384 + ct * 2048 + col * 128;
            bf16x8 ach0 = *(const bf16x8*)(lds + arow + ((((0 * 4) + grp) ^ (col & 7)) << 4));
            bf16x8 ach1 = *(const bf16x8*)(lds + arow + ((((1 * 4) + grp) ^ (col & 7)) << 4));
            bf16x8 acl0 = *(const bf16x8*)(lds + arow + 8192 + ((((0 * 4) + grp) ^ (col & 7)) << 4));
            bf16x8 acl1 = *(const bf16x8*)(lds + arow + 8192 + ((((1 * 4) + grp) ^ (col & 7)) << 4));
            f32x4 hv = *(const f32x4*)(lds + 32768 + b * 256 + ct * 64 + grp * 16);

            f32x4 acc0 = hv, acc1 = hv;
            acc0 = __builtin_amdgcn_mfma_f32_16x16x32_bf16(ach0, zh[0][0], acc0, 0, 0, 0);
            acc1 = __builtin_amdgcn_mfma_f32_16x16x32_bf16(ach0, zh[1][0], acc1, 0, 0, 0);
            acc0 = __builtin_amdgcn_mfma_f32_16x16x32_bf16(ach1, zh[0][1], acc0, 0, 0, 0);
            acc1 = __builtin_amdgcn_mfma_f32_16x16x32_bf16(ach1, zh[1][1], acc1, 0, 0, 0);
            acc0 = __builtin_amdgcn_mfma_f32_16x16x32_bf16(ach0, zl[0][0], acc0, 0, 0, 0);
            acc1 = __builtin_amdgcn_mfma_f32_16x16x32_bf16(ach0, zl[1][0], acc1, 0, 0, 0);
            acc0 = __builtin_amdgcn_mfma_f32_16x16x32_bf16(ach1, zl[0][1], acc0, 0, 0, 0);
            acc1 = __builtin_amdgcn_mfma_f32_16x16x32_bf16(ach1, zl[1][1], acc1, 0, 0, 0);
            acc0 = __builtin_amdgcn_mfma_f32_16x16x32_bf16(acl0, zh[0][0], acc0, 0, 0, 0);
            acc1 = __builtin_amdgcn_mfma_f32_16x16x32_bf16(acl0, zh[1][0], acc1, 0, 0, 0);
            acc0 = __builtin_amdgcn_mfma_f32_16x16x32_bf16(acl1, zh[0][1], acc0, 0, 0, 0);
            acc1 = __builtin_amdgcn_mfma_f32_16x16x32_bf16(acl1, zh[1][1], acc1, 0, 0, 0);

            const int kb = cc * 64 + ct * 16 + grp * 4;
#pragma unroll
            for (int j = 0; j < 4; ++j) {
                float s0 = acc0[j], s1 = acc1[j];
                bool lt0 = s0 < m1[0], lt1 = s1 < m1[1];
                m2[0] = fminf(m2[0], fmaxf(s0, m1[0]));
                m2[1] = fminf(m2[1], fmaxf(s1, m1[1]));
                ki[0] = lt0 ? (kb + j) : ki[0];
                ki[1] = lt1 ? (kb + j) : ki[1];
                m1[0] = fminf(m1[0], s0);
                m1[1] = fminf(m1[1], s1);
            }
        }
        __syncthreads();
    }

#pragma unroll
    for (int d = 16; d <= 32; d <<= 1) {
#pragma unroll
        for (int tt = 0; tt < 2; ++tt) {
            float om1 = __shfl_xor(m1[tt], d, 64);
            float om2 = __shfl_xor(m2[tt], d, 64);
            int   oki = __shfl_xor(ki[tt], d, 64);
            m2[tt] = fminf(fminf(m2[tt], om2), fmaxf(m1[tt], om1));
            ki[tt] = (om1 < m1[tt]) ? oki : ki[tt];
            m1[tt] = fminf(m1[tt], om1);
        }
    }
    if (lane < 16) {
#pragma unroll
        for (int tt = 0; tt < 2; ++tt) {
            int t = tbase + tt * 16 + lane;
            bool flag = (m2[tt] - m1[tt]) < EPS_FLAG;
            out[OUT_IDX + t] = flag ? -(float)(ki[tt] + 1) : (float)ki[tt];
        }
    }
}

// Kernel 2: streaming gather, float4-vectorized (16B/lane). A wave covers
// 4 token rows per iteration; 4 iterations per thread. Unflagged tokens:
// gather/SSE/histogram (padded counters). Flagged: skip + append to qlist.
__global__ __launch_bounds__(256) void vq_gather(
    const float* __restrict__ ze, const float* __restrict__ cb,
    float* __restrict__ out, double* __restrict__ sse_g, int* __restrict__ counts,
    int* __restrict__ qcount, int* __restrict__ qlist) {
    const int base = blockIdx.x * 256 + threadIdx.x;
    const int stride = 2048 * 256;
    double lsse = 0.0;
#pragma unroll
    for (int it = 0; it < 4; ++it) {
        int gid4 = base + it * stride;     // float4 index, 0..2M-1
        int n  = gid4 >> 4;                // token
        int d4 = gid4 & 15;                // float4 slot within row
        float fidx = out[OUT_IDX + n];
        if (fidx < 0.0f) {
            if (d4 == 0) { int slot = atomicAdd(qcount, 1); qlist[slot] = n; }
            continue;
        }
        int idx = (int)fidx;
        float4 q  = *(const float4*)(cb + idx * DIM + d4 * 4);
        float4 zv = *(const float4*)(ze + (size_t)n * DIM + d4 * 4);
        *(float4*)(out + (size_t)n * DIM + d4 * 4) = q;
        double dx = (double)q.x - (double)zv.x;
        double dy = (double)q.y - (double)zv.y;
        double dz = (double)q.z - (double)zv.z;
        double dw = (double)q.w - (double)zv.w;
        lsse = fma(dx, dx, lsse); lsse = fma(dy, dy, lsse);
        lsse = fma(dz, dz, lsse); lsse = fma(dw, dw, lsse);
        if (d4 == 0) atomicAdd(&counts[idx * 16], 1);   // padded: 1 ctr / 64B line
    }
#pragma unroll
    for (int off = 32; off > 0; off >>= 1)
        lsse += __shfl_down(lsse, off, 64);
    __shared__ double red[4];
    if ((threadIdx.x & 63) == 0) red[threadIdx.x >> 6] = lsse;
    __syncthreads();
    if (threadIdx.x == 0)
        atomicAdd(sse_g, (red[0] + red[1]) + (red[2] + red[3]));
}

// Kernel 3: rescue (r14 logic frozen; counts padded) + last-block finalize.
__global__ __launch_bounds__(512) void vq_rescue(
    const float* __restrict__ ze, const float* __restrict__ cb,
    const float* __restrict__ h_g, const int* __restrict__ qcount,
    const int* __restrict__ qlist, float* __restrict__ out,
    double* __restrict__ sse_g, int* __restrict__ counts,
    int* __restrict__ done) {
    __shared__ __align__(16) float4 cbl[512 * 17];          // 139,264 B
    __shared__ float zst[8][64];
    __shared__ unsigned long long keys[8][64];
    __shared__ float hl[NEMB];
    __shared__ double red[8];
    __shared__ int flagS;
    const int tid  = threadIdx.x;
    const int lane = tid & 63;
    const int wid  = tid >> 6;
    const int nq   = *qcount;
    const int per  = (nq + 255) >> 8;
    const int i0   = blockIdx.x * per;
    const int iend = (i0 + per < nq) ? (i0 + per) : nq;
    double lsse = 0.0;

    if (i0 < iend) {   // block-uniform
        for (int i = tid; i < NEMB; i += 512) hl[i] = h_g[i];
        const float4* cb4 = (const float4*)cb;

        for (int hf = 0; hf < 2; ++hf) {
            __syncthreads();
#pragma unroll
            for (int j = 0; j < 16; ++j) {
                int f = tid + j * 512;
                int code = f >> 4, d4 = f & 15;
                cbl[code * 17 + d4] = cb4[(size_t)(hf * 512 + code) * 16 + d4];
            }
            __syncthreads();

            for (int i = i0 + wid; i < iend; i += 8) {
                const int t = qlist[i];
                const int slot = (i - i0) >> 3;

                zst[wid][lane] = ze[(size_t)t * 64 + lane];
                __builtin_amdgcn_wave_barrier();
                asm volatile("s_waitcnt lgkmcnt(0)" ::: "memory");
                __builtin_amdgcn_sched_barrier(0);

                float sz;
#define GZ(d) (zst[wid][d])
                NP_PAIRWISE_SQ64(GZ, sz);
#undef GZ

                float acc[8] = {0.f, 0.f, 0.f, 0.f, 0.f, 0.f, 0.f, 0.f};
                const float4* zr4 = (const float4*)zst[wid];
#pragma unroll
                for (int d4 = 0; d4 < 16; ++d4) {
                    float4 zq = zr4[d4];
#pragma unroll
                    for (int cc = 0; cc < 8; ++cc) {
                        float4 cv = cbl[(lane + 64 * cc) * 17 + d4];
                        acc[cc] = fmaf(cv.x, zq.x, acc[cc]);
                        acc[cc] = fmaf(cv.y, zq.y, acc[cc]);
                        acc[cc] = fmaf(cv.z, zq.z, acc[cc]);
                        acc[cc] = fmaf(cv.w, zq.w, acc[cc]);
                    }
                }
                unsigned long long key = ~0ull;
#pragma unroll
                for (int cc = 0; cc < 8; ++cc) {
                    unsigned k = (unsigned)(hf * 512 + lane + 64 * cc);
                    float dk = (sz + hl[k]) - 2.0f * acc[cc];   // frozen formula
                    unsigned long long c =
                        ((unsigned long long)__float_as_uint(dk) << 32) | k;
                    key = c < key ? c : key;
                }
#pragma unroll
                for (int dd = 1; dd < 64; dd <<= 1) {
                    unsigned long long o = __shfl_xor(key, dd, 64);
                    key = o < key ? o : key;
                }
                if (hf == 0) {
                    if (lane == 0) keys[wid][slot] = key;
                } else {
                    unsigned long long k0 = keys[wid][slot];  // LDS broadcast
                    if (k0 < key) key = k0;
                    int newk = (int)(unsigned)(key & 0xFFFFFFFFull);
                    // own this token end-to-end
                    float q  = cb[newk * 64 + lane];
                    float zv = zst[wid][lane];
                    out[(size_t)t * 64 + lane] = q;
                    double diff = (double)q - (double)zv;
                    lsse = fma(diff, diff, lsse);
                    if (lane == 0) {
                        out[OUT_IDX + t] = (float)newk;
                        atomicAdd(&counts[newk * 16], 1);
                    }
                }
            }
        }
    }

    // SSE contribution (blocks with work), then all blocks hit done-counter
#pragma unroll
    for (int off = 32; off > 0; off >>= 1)
        lsse += __shfl_down(lsse, off, 64);
    if (lane == 0) red[wid] = lsse;
    __syncthreads();
    if (tid == 0) {
        double bs = ((red[0] + red[1]) + (red[2] + red[3]))
                  + ((red[4] + red[5]) + (red[6] + red[7]));
        if (bs != 0.0) atomicAdd(sse_g, bs);
        __threadfence();
        flagS = (atomicAdd(done, 1) == 255);
    }
    __syncthreads();

    // last block finalizes loss + perplexity
    if (flagS) {
        __threadfence();
        double* red2 = (double*)cbl;   // staging LDS dead here
        double local = 0.0;
        for (int k = tid; k < NEMB; k += 512) {
            int cv = __hip_atomic_load(&counts[k * 16], __ATOMIC_RELAXED, __HIP_MEMORY_SCOPE_AGENT);
            double p = (double)cv / (double)NTOK;
            local += p * log(p + 1e-10);
        }
        red2[tid] = local;
        __syncthreads();
        for (int s = 256; s > 0; s >>= 1) {
            if (tid < s) red2[tid] += red2[tid + s];
            __syncthreads();
        }
        if (tid == 0) {
            double sv = __hip_atomic_load(sse_g, __ATOMIC_RELAXED, __HIP_MEMORY_SCOPE_AGENT);
            double mse = sv / ((double)NTOK * (double)DIM);
            out[OUT_LOSS] = (float)(1.25 * mse);
            out[OUT_PERP] = (float)exp(-red2[0]);
        }
    }
}

extern "C" void kernel_launch(void* const* d_in, const int* in_sizes, int n_in,
                              void* d_out, int out_size, void* d_ws, size_t ws_size,
                              hipStream_t stream) {
    const float* ze = (const float*)d_in[0];
    const float* cb = (const float*)d_in[1];
    float* out = (float*)d_out;

    char* w = (char*)d_ws;
    double*         sse    = (double*)w;                     // @0
    int*            counts = (int*)(w + 64);                 // 64 KiB (padded)
    int*            qcount = (int*)(w + 65600);
    int*            done   = (int*)(w + 65608);
    float*          h      = (float*)(w + 65664);            // 4 KiB
    unsigned short* ch     = (unsigned short*)(w + 69760);   // 128 KiB
    unsigned short* cl     = (unsigned short*)(w + 200832);  // 128 KiB
    int*            qlist  = (int*)(w + 331904);             // 512 KiB

    vq_prep<<<NEMB / 256, 256, 0, stream>>>(cb, h, ch, cl, sse, counts, qcount, done);
    vq_screen<<<NTOK / 256, 512, 0, stream>>>(ze, ch, cl, h, out);
    vq_gather<<<2048, 256, 0, stream>>>(ze, cb, out, sse, counts, qcount, qlist);
    vq_rescue<<<256, 512, 0, stream>>>(ze, cb, h, qcount, qlist, out, sse, counts, done);
}

// Round 16
// 128.833 us; speedup vs baseline: 2.0799x; 1.2573x over previous
//
#include <hip/hip_runtime.h>
#include <math.h>

// VectorQuantizer: N=131072 tokens, K=1024 codes, D=64, fp32.
// Out layout (flat): z_q_st[N*D] | loss | perplexity | indices[N] (as f32)
#define NTOK 131072
#define NEMB 1024
#define DIM  64
#define OUT_LOSS (NTOK * DIM)
#define OUT_PERP (OUT_LOSS + 1)
#define OUT_IDX  (OUT_LOSS + 2)

#define EPS_FLAG 6e-5f   // screen ambiguity margin (frozen; passed r3-r15)

typedef short bf16x8 __attribute__((ext_vector_type(8)));
typedef float f32x4  __attribute__((ext_vector_type(4)));

// ---- numpy fp32 semantics helpers (frozen from round 2 -- PASSED) ----------
__device__ __forceinline__ float sqb(float x) {
    float y = x * x;
    asm volatile("" : "+v"(y));
    return y;
}
// numpy pairwise_sum for n=64 contiguous: 8 accumulators stride 8, then
// ((r0+r1)+(r2+r3))+((r4+r5)+(r6+r7)).
#define NP_PAIRWISE_SQ64(GET, RES)                                     \
    do {                                                               \
        float r0 = sqb(GET(0)), r1 = sqb(GET(1)), r2 = sqb(GET(2)),    \
              r3 = sqb(GET(3)), r4 = sqb(GET(4)), r5 = sqb(GET(5)),    \
              r6 = sqb(GET(6)), r7 = sqb(GET(7));                      \
        _Pragma("unroll")                                              \
        for (int i = 8; i < 64; i += 8) {                              \
            r0 += sqb(GET(i + 0)); r1 += sqb(GET(i + 1));              \
            r2 += sqb(GET(i + 2)); r3 += sqb(GET(i + 3));              \
            r4 += sqb(GET(i + 4)); r5 += sqb(GET(i + 5));              \
            r6 += sqb(GET(i + 6)); r7 += sqb(GET(i + 7));              \
        }                                                              \
        RES = ((r0 + r1) + (r2 + r3)) + ((r4 + r5) + (r6 + r7));       \
    } while (0)

__device__ __forceinline__ unsigned short f2bf_rne(float x) {
    unsigned u = __float_as_uint(x);
    u += 0x7FFFu + ((u >> 16) & 1u);   // round-to-nearest-even
    return (unsigned short)(u >> 16);
}
__device__ __forceinline__ float bf2f(unsigned short b) {
    return __uint_as_float(((unsigned)b) << 16);
}

// ws layout (bytes):
//   0:      sse double
//   64:     counts int[1024*16]  (64 KiB, one counter per 64B line)
//   65600:  done int
//   65664:  h float[1024]        (4 KiB)
//   69760:  ch bf16[1024*64]     (128 KiB)
//   200832: cl bf16[1024*64]     (128 KiB)

// Kernel 0: h[k] np-exact; ch/cl bf16 split of (-2c); block 0 zeroes accums.
__global__ void vq_prep(const float* __restrict__ cb, float* __restrict__ h,
                        unsigned short* __restrict__ ch, unsigned short* __restrict__ cl,
                        double* __restrict__ sse, int* __restrict__ counts,
                        int* __restrict__ done) {
    if (blockIdx.x == 0) {
        if (threadIdx.x == 0) { *sse = 0.0; *done = 0; }
        for (int i = threadIdx.x; i < NEMB * 16; i += 256) counts[i] = 0;
    }
    int k = blockIdx.x * 256 + threadIdx.x;
    if (k >= NEMB) return;
    float c[64];
    const float4* p = (const float4*)(cb + k * DIM);
#pragma unroll
    for (int q = 0; q < 16; ++q) {
        float4 v = p[q];
        c[4 * q] = v.x; c[4 * q + 1] = v.y; c[4 * q + 2] = v.z; c[4 * q + 3] = v.w;
    }
    float hk;
#define GETC(d) (c[d])
    NP_PAIRWISE_SQ64(GETC, hk);
#undef GETC
    h[k] = hk;
#pragma unroll
    for (int b = 0; b < 8; ++b) {
        unsigned uhv[4], ulv[4];
#pragma unroll
        for (int e = 0; e < 4; ++e) {
            float x0 = -2.0f * c[b * 8 + e * 2 + 0];
            float x1 = -2.0f * c[b * 8 + e * 2 + 1];
            unsigned short h0 = f2bf_rne(x0), h1 = f2bf_rne(x1);
            unsigned short l0 = f2bf_rne(x0 - bf2f(h0)), l1 = f2bf_rne(x1 - bf2f(h1));
            uhv[e] = (unsigned)h0 | ((unsigned)h1 << 16);
            ulv[e] = (unsigned)l0 | ((unsigned)l1 << 16);
        }
        *(uint4*)(ch + k * 64 + b * 8) = make_uint4(uhv[0], uhv[1], uhv[2], uhv[3]);
        *(uint4*)(cl + k * 64 + b * 8) = make_uint4(ulv[0], ulv[1], ulv[2], ulv[3]);
    }
}

// Kernel 1: MFMA screen (core byte-frozen r13-r15) + register-fed float4
// gather/SSE/histogram epilogue for UNFLAGGED tokens (no idx read-back, no
// separate gather pass). Flagged tokens: sign-encoded idx, rows left to rescue.
__global__ __launch_bounds__(512) void vq_screen(
    const float*          __restrict__ ze,
    const float*          __restrict__ cb,
    const unsigned short* __restrict__ ch_g,
    const unsigned short* __restrict__ cl_g,
    const float*          __restrict__ h_g,
    float*                __restrict__ out,
    double*               __restrict__ sse_g,
    int*                  __restrict__ counts) {
    __shared__ __align__(16) char lds[2 * 16384 + 2 * 256 + 64];
    const int tid  = threadIdx.x;
    const int lane = tid & 63;
    const int wid  = tid >> 6;
    const int col  = lane & 15;
    const int grp  = lane >> 4;
    const int tbase = blockIdx.x * 256 + wid * 32;

    bf16x8 zh[2][2], zl[2][2];
#pragma unroll
    for (int tt = 0; tt < 2; ++tt)
#pragma unroll
        for (int s = 0; s < 2; ++s) {
            const float* zp = ze + (size_t)(tbase + tt * 16 + col) * 64 + s * 32 + grp * 8;
            float4 v0 = *(const float4*)(zp);
            float4 v1 = *(const float4*)(zp + 4);
            float zv[8] = {v0.x, v0.y, v0.z, v0.w, v1.x, v1.y, v1.z, v1.w};
            bf16x8 hfr, lfr;
#pragma unroll
            for (int j = 0; j < 8; ++j) {
                unsigned short hb = f2bf_rne(zv[j]);
                unsigned short lb = f2bf_rne(zv[j] - bf2f(hb));
                hfr[j] = (short)hb;
                lfr[j] = (short)lb;
            }
            zh[tt][s] = hfr;
            zl[tt][s] = lfr;
        }

    float m1[2] = {INFINITY, INFINITY}, m2[2] = {INFINITY, INFINITY};
    int   ki[2] = {0, 0};

#define STAGE(cc, b)                                                            \
    do {                                                                        \
        int i = tid;                                                            \
        int4 va = *(const int4*)((const char*)ch_g + (cc) * 8192 + i * 16);     \
        int4 vb = *(const int4*)((const char*)cl_g + (cc) * 8192 + i * 16);     \
        int r = i >> 3, slot = i & 7;                                           \
        int st = r >> 4, row = r & 15;                                          \
        int off = (b) * 16384 + st * 2048 + row * 128 + ((slot ^ (row & 7)) << 4); \
        *(int4*)(lds + off) = va;                                               \
        *(int4*)(lds + off + 8192) = vb;                                        \
        if (i < 64) *(float*)(lds + 32768 + (b) * 256 + i * 4) = h_g[(cc) * 64 + i]; \
    } while (0)

    STAGE(0, 0);
    __syncthreads();

    for (int cc = 0; cc < 16; ++cc) {
        int b = cc & 1;
        if (cc + 1 < 16) STAGE(cc + 1, b ^ 1);

        for (int ct = 0; ct < 4; ++ct) {
            const int arow = b * 16384 + ct * 2048 + col * 128;
            bf16x8 ach0 = *(const bf16x8*)(lds + arow + ((((0 * 4) + grp) ^ (col & 7)) << 4));
            bf16x8 ach1 = *(const bf16x8*)(lds + arow + ((((1 * 4) + grp) ^ (col & 7)) << 4));
            bf16x8 acl0 = *(const bf16x8*)(lds + arow + 8192 + ((((0 * 4) + grp) ^ (col & 7)) << 4));
            bf16x8 acl1 = *(const bf16x8*)(lds + arow + 8192 + ((((1 * 4) + grp) ^ (col & 7)) << 4));
            f32x4 hv = *(const f32x4*)(lds + 32768 + b * 256 + ct * 64 + grp * 16);

            f32x4 acc0 = hv, acc1 = hv;
            acc0 = __builtin_amdgcn_mfma_f32_16x16x32_bf16(ach0, zh[0][0], acc0, 0, 0, 0);
            acc1 = __builtin_amdgcn_mfma_f32_16x16x32_bf16(ach0, zh[1][0], acc1, 0, 0, 0);
            acc0 = __builtin_amdgcn_mfma_f32_16x16x32_bf16(ach1, zh[0][1], acc0, 0, 0, 0);
            acc1 = __builtin_amdgcn_mfma_f32_16x16x32_bf16(ach1, zh[1][1], acc1, 0, 0, 0);
            acc0 = __builtin_amdgcn_mfma_f32_16x16x32_bf16(ach0, zl[0][0], acc0, 0, 0, 0);
            acc1 = __builtin_amdgcn_mfma_f32_16x16x32_bf16(ach0, zl[1][0], acc1, 0, 0, 0);
            acc0 = __builtin_amdgcn_mfma_f32_16x16x32_bf16(ach1, zl[0][1], acc0, 0, 0, 0);
            acc1 = __builtin_amdgcn_mfma_f32_16x16x32_bf16(ach1, zl[1][1], acc1, 0, 0, 0);
            acc0 = __builtin_amdgcn_mfma_f32_16x16x32_bf16(acl0, zh[0][0], acc0, 0, 0, 0);
            acc1 = __builtin_amdgcn_mfma_f32_16x16x32_bf16(acl0, zh[1][0], acc1, 0, 0, 0);
            acc0 = __builtin_amdgcn_mfma_f32_16x16x32_bf16(acl1, zh[0][1], acc0, 0, 0, 0);
            acc1 = __builtin_amdgcn_mfma_f32_16x16x32_bf16(acl1, zh[1][1], acc1, 0, 0, 0);

            const int kb = cc * 64 + ct * 16 + grp * 4;
#pragma unroll
            for (int j = 0; j < 4; ++j) {
                float s0 = acc0[j], s1 = acc1[j];
                bool lt0 = s0 < m1[0], lt1 = s1 < m1[1];
                m2[0] = fminf(m2[0], fmaxf(s0, m1[0]));
                m2[1] = fminf(m2[1], fmaxf(s1, m1[1]));
                ki[0] = lt0 ? (kb + j) : ki[0];
                ki[1] = lt1 ? (kb + j) : ki[1];
                m1[0] = fminf(m1[0], s0);
                m1[1] = fminf(m1[1], s1);
            }
        }
        __syncthreads();
    }

#pragma unroll
    for (int d = 16; d <= 32; d <<= 1) {
#pragma unroll
        for (int tt = 0; tt < 2; ++tt) {
            float om1 = __shfl_xor(m1[tt], d, 64);
            float om2 = __shfl_xor(m2[tt], d, 64);
            int   oki = __shfl_xor(ki[tt], d, 64);
            m2[tt] = fminf(fminf(m2[tt], om2), fmaxf(m1[tt], om1));
            ki[tt] = (om1 < m1[tt]) ? oki : ki[tt];
            m1[tt] = fminf(m1[tt], om1);
        }
    }
    // after butterfly, every lane holds m1/m2/ki for token col = lane&15
    unsigned flagpack = ((m2[0] - m1[0] < EPS_FLAG) ? 1u : 0u)
                      | ((m2[1] - m1[1] < EPS_FLAG) ? 2u : 0u);
    if (lane < 16) {
#pragma unroll
        for (int tt = 0; tt < 2; ++tt) {
            int t = tbase + tt * 16 + lane;
            bool flag = (flagpack >> tt) & 1u;
            out[OUT_IDX + t] = flag ? -(float)(ki[tt] + 1) : (float)ki[tt];
        }
    }

    // ---- register-fed float4 gather/SSE/histogram for UNFLAGGED tokens ----
    // rows j=0..31 of this wave; 4 rows per iter (grp selects row, col=d4 slot)
    double lsse = 0.0;
    const int d4 = lane & 15;
#pragma unroll
    for (int iter = 0; iter < 8; ++iter) {
        const int j   = iter * 4 + grp;       // row in [0,32)
        const int tt  = iter >> 2;            // uniform per iter
        const int src = j & 15;
        int k = __shfl(ki[tt], src, 64);
        unsigned fp = __shfl(flagpack, src, 64);
        if (!((fp >> tt) & 1u)) {
            const int t = tbase + j;
            float4 q  = *(const float4*)(cb + k * DIM + d4 * 4);
            float4 zv = *(const float4*)(ze + (size_t)t * DIM + d4 * 4);
            *(float4*)(out + (size_t)t * DIM + d4 * 4) = q;
            double dx = (double)q.x - (double)zv.x;
            double dy = (double)q.y - (double)zv.y;
            double dz = (double)q.z - (double)zv.z;
            double dw = (double)q.w - (double)zv.w;
            lsse = fma(dx, dx, lsse); lsse = fma(dy, dy, lsse);
            lsse = fma(dz, dz, lsse); lsse = fma(dw, dw, lsse);
            if (d4 == 0) atomicAdd(&counts[k * 16], 1);   // one per row
        }
    }
#pragma unroll
    for (int off = 32; off > 0; off >>= 1)
        lsse += __shfl_down(lsse, off, 64);
    double* red = (double*)(lds + 33280);
    if (lane == 0) red[wid] = lsse;
    __syncthreads();
    if (tid == 0) {
        double bs = ((red[0] + red[1]) + (red[2] + red[3]))
                  + ((red[4] + red[5]) + (red[6] + red[7]));
        atomicAdd(sse_g, bs);
    }
}

// Kernel 2: rescue. Block owns 512 tokens: reads its idx slice, builds a
// LOCAL worklist of flagged tokens (no global qlist), stages fp32 codebook
// half-by-half (r8-proven layout), rescues end-to-end (row/SSE/hist), then
// done-counter last-block finalize.
__global__ __launch_bounds__(512) void vq_rescue(
    const float* __restrict__ ze, const float* __restrict__ cb,
    const float* __restrict__ h_g, float* __restrict__ out,
    double* __restrict__ sse_g, int* __restrict__ counts,
    int* __restrict__ done) {
    __shared__ __align__(16) float4 cbl[512 * 17];          // 139,264 B
    __shared__ float zst[8][64];
    __shared__ unsigned long long keys[8][64];
    __shared__ float hl[NEMB];
    __shared__ int loc[512];
    __shared__ int nloc;
    __shared__ double red[8];
    __shared__ int flagS;
    const int tid  = threadIdx.x;
    const int lane = tid & 63;
    const int wid  = tid >> 6;
    const int tbase = blockIdx.x * 512;

    if (tid == 0) nloc = 0;
    for (int i = tid; i < NEMB; i += 512) hl[i] = h_g[i];
    __syncthreads();
    float fidx = out[OUT_IDX + tbase + tid];
    if (fidx < 0.0f) { int s = atomicAdd(&nloc, 1); loc[s] = tid; }
    __syncthreads();
    const int nq = nloc;
    double lsse = 0.0;

    if (nq > 0) {
        const float4* cb4 = (const float4*)cb;
        for (int hf = 0; hf < 2; ++hf) {
            __syncthreads();
#pragma unroll
            for (int j = 0; j < 16; ++j) {
                int f = tid + j * 512;
                int code = f >> 4, d4 = f & 15;
                cbl[code * 17 + d4] = cb4[(size_t)(hf * 512 + code) * 16 + d4];
            }
            __syncthreads();

            for (int i = wid; i < nq; i += 8) {
                const int t = tbase + loc[i];
                const int slot = i >> 3;

                zst[wid][lane] = ze[(size_t)t * 64 + lane];
                __builtin_amdgcn_wave_barrier();
                asm volatile("s_waitcnt lgkmcnt(0)" ::: "memory");
                __builtin_amdgcn_sched_barrier(0);

                float sz;
#define GZ(d) (zst[wid][d])
                NP_PAIRWISE_SQ64(GZ, sz);
#undef GZ

                float acc[8] = {0.f, 0.f, 0.f, 0.f, 0.f, 0.f, 0.f, 0.f};
                const float4* zr4 = (const float4*)zst[wid];
#pragma unroll
                for (int d4 = 0; d4 < 16; ++d4) {
                    float4 zq = zr4[d4];
#pragma unroll
                    for (int cc = 0; cc < 8; ++cc) {
                        float4 cv = cbl[(lane + 64 * cc) * 17 + d4];
                        acc[cc] = fmaf(cv.x, zq.x, acc[cc]);
                        acc[cc] = fmaf(cv.y, zq.y, acc[cc]);
                        acc[cc] = fmaf(cv.z, zq.z, acc[cc]);
                        acc[cc] = fmaf(cv.w, zq.w, acc[cc]);
                    }
                }
                unsigned long long key = ~0ull;
#pragma unroll
                for (int cc = 0; cc < 8; ++cc) {
                    unsigned k = (unsigned)(hf * 512 + lane + 64 * cc);
                    float dk = (sz + hl[k]) - 2.0f * acc[cc];   // frozen formula
                    unsigned long long c =
                        ((unsigned long long)__float_as_uint(dk) << 32) | k;
                    key = c < key ? c : key;
                }
#pragma unroll
                for (int dd = 1; dd < 64; dd <<= 1) {
                    unsigned long long o = __shfl_xor(key, dd, 64);
                    key = o < key ? o : key;
                }
                if (hf == 0) {
                    if (lane == 0) keys[wid][slot] = key;
                } else {
                    unsigned long long k0 = keys[wid][slot];  // LDS broadcast
                    if (k0 < key) key = k0;
                    int newk = (int)(unsigned)(key & 0xFFFFFFFFull);
                    // own this token end-to-end
                    float q  = cb[newk * 64 + lane];
                    float zv = zst[wid][lane];
                    out[(size_t)t * 64 + lane] = q;
                    double diff = (double)q - (double)zv;
                    lsse = fma(diff, diff, lsse);
                    if (lane == 0) {
                        out[OUT_IDX + t] = (float)newk;
                        atomicAdd(&counts[newk * 16], 1);
                    }
                }
            }
        }
    }

    // SSE contribution, then all blocks hit done-counter
#pragma unroll
    for (int off = 32; off > 0; off >>= 1)
        lsse += __shfl_down(lsse, off, 64);
    if (lane == 0) red[wid] = lsse;
    __syncthreads();
    if (tid == 0) {
        double bs = ((red[0] + red[1]) + (red[2] + red[3]))
                  + ((red[4] + red[5]) + (red[6] + red[7]));
        if (bs != 0.0) atomicAdd(sse_g, bs);
        __threadfence();
        flagS = (atomicAdd(done, 1) == 255);
    }
    __syncthreads();

    // last block finalizes loss + perplexity
    if (flagS) {
        __threadfence();
        double* red2 = (double*)cbl;   // staging LDS dead here
        double local = 0.0;
        for (int k = tid; k < NEMB; k += 512) {
            int cv = __hip_atomic_load(&counts[k * 16], __ATOMIC_RELAXED, __HIP_MEMORY_SCOPE_AGENT);
            double p = (double)cv / (double)NTOK;
            local += p * log(p + 1e-10);
        }
        red2[tid] = local;
        __syncthreads();
        for (int s = 256; s > 0; s >>= 1) {
            if (tid < s) red2[tid] += red2[tid + s];
            __syncthreads();
        }
        if (tid == 0) {
            double sv = __hip_atomic_load(sse_g, __ATOMIC_RELAXED, __HIP_MEMORY_SCOPE_AGENT);
            double mse = sv / ((double)NTOK * (double)DIM);
            out[OUT_LOSS] = (float)(1.25 * mse);
            out[OUT_PERP] = (float)exp(-red2[0]);
        }
    }
}

extern "C" void kernel_launch(void* const* d_in, const int* in_sizes, int n_in,
                              void* d_out, int out_size, void* d_ws, size_t ws_size,
                              hipStream_t stream) {
    const float* ze = (const float*)d_in[0];
    const float* cb = (const float*)d_in[1];
    float* out = (float*)d_out;

    char* w = (char*)d_ws;
    double*         sse    = (double*)w;                     // @0
    int*            counts = (int*)(w + 64);                 // 64 KiB (padded)
    int*            done   = (int*)(w + 65600);
    float*          h      = (float*)(w + 65664);            // 4 KiB
    unsigned short* ch     = (unsigned short*)(w + 69760);   // 128 KiB
    unsigned short* cl     = (unsigned short*)(w + 200832);  // 128 KiB

    vq_prep<<<NEMB / 256, 256, 0, stream>>>(cb, h, ch, cl, sse, counts, done);
    vq_screen<<<NTOK / 256, 512, 0, stream>>>(ze, cb, ch, cl, h, out, sse, counts);
    vq_rescue<<<NTOK / 512, 512, 0, stream>>>(ze, cb, h, out, sse, counts, done);
}

// Round 17
// 126.229 us; speedup vs baseline: 2.1229x; 1.0206x over previous
//
#include <hip/hip_runtime.h>
#include <math.h>

// VectorQuantizer: N=131072 tokens, K=1024 codes, D=64, fp32.
// Out layout (flat): z_q_st[N*D] | loss | perplexity | indices[N] (as f32)
#define NTOK 131072
#define NEMB 1024
#define DIM  64
#define OUT_LOSS (NTOK * DIM)
#define OUT_PERP (OUT_LOSS + 1)
#define OUT_IDX  (OUT_LOSS + 2)

#define EPS_FLAG 6e-5f   // screen ambiguity margin (frozen; passed r3-r16)

typedef short bf16x8 __attribute__((ext_vector_type(8)));
typedef float f32x4  __attribute__((ext_vector_type(4)));
typedef const __attribute__((address_space(1))) void* gas_t;
typedef __attribute__((address_space(3))) void* las_t;

// ---- numpy fp32 semantics helpers (frozen from round 2 -- PASSED) ----------
__device__ __forceinline__ float sqb(float x) {
    float y = x * x;
    asm volatile("" : "+v"(y));
    return y;
}
// numpy pairwise_sum for n=64 contiguous: 8 accumulators stride 8, then
// ((r0+r1)+(r2+r3))+((r4+r5)+(r6+r7)).
#define NP_PAIRWISE_SQ64(GET, RES)                                     \
    do {                                                               \
        float r0 = sqb(GET(0)), r1 = sqb(GET(1)), r2 = sqb(GET(2)),    \
              r3 = sqb(GET(3)), r4 = sqb(GET(4)), r5 = sqb(GET(5)),    \
              r6 = sqb(GET(6)), r7 = sqb(GET(7));                      \
        _Pragma("unroll")                                              \
        for (int i = 8; i < 64; i += 8) {                              \
            r0 += sqb(GET(i + 0)); r1 += sqb(GET(i + 1));              \
            r2 += sqb(GET(i + 2)); r3 += sqb(GET(i + 3));              \
            r4 += sqb(GET(i + 4)); r5 += sqb(GET(i + 5));              \
            r6 += sqb(GET(i + 6)); r7 += sqb(GET(i + 7));              \
        }                                                              \
        RES = ((r0 + r1) + (r2 + r3)) + ((r4 + r5) + (r6 + r7));       \
    } while (0)

__device__ __forceinline__ unsigned short f2bf_rne(float x) {
    unsigned u = __float_as_uint(x);
    u += 0x7FFFu + ((u >> 16) & 1u);   // round-to-nearest-even
    return (unsigned short)(u >> 16);
}
__device__ __forceinline__ float bf2f(unsigned short b) {
    return __uint_as_float(((unsigned)b) << 16);
}

// ws layout (bytes):
//   0:      sse double
//   64:     counts int[1024*16]  (64 KiB, one counter per 64B line)
//   65600:  done int
//   65664:  h float[1024]        (4 KiB)
//   69760:  ch bf16[1024*64]     (128 KiB)
//   200832: cl bf16[1024*64]     (128 KiB)

// Kernel 0: h[k] np-exact; ch/cl bf16 split of (-2c); block 0 zeroes accums.
__global__ void vq_prep(const float* __restrict__ cb, float* __restrict__ h,
                        unsigned short* __restrict__ ch, unsigned short* __restrict__ cl,
                        double* __restrict__ sse, int* __restrict__ counts,
                        int* __restrict__ done) {
    if (blockIdx.x == 0) {
        if (threadIdx.x == 0) { *sse = 0.0; *done = 0; }
        for (int i = threadIdx.x; i < NEMB * 16; i += 256) counts[i] = 0;
    }
    int k = blockIdx.x * 256 + threadIdx.x;
    if (k >= NEMB) return;
    float c[64];
    const float4* p = (const float4*)(cb + k * DIM);
#pragma unroll
    for (int q = 0; q < 16; ++q) {
        float4 v = p[q];
        c[4 * q] = v.x; c[4 * q + 1] = v.y; c[4 * q + 2] = v.z; c[4 * q + 3] = v.w;
    }
    float hk;
#define GETC(d) (c[d])
    NP_PAIRWISE_SQ64(GETC, hk);
#undef GETC
    h[k] = hk;
#pragma unroll
    for (int b = 0; b < 8; ++b) {
        unsigned uhv[4], ulv[4];
#pragma unroll
        for (int e = 0; e < 4; ++e) {
            float x0 = -2.0f * c[b * 8 + e * 2 + 0];
            float x1 = -2.0f * c[b * 8 + e * 2 + 1];
            unsigned short h0 = f2bf_rne(x0), h1 = f2bf_rne(x1);
            unsigned short l0 = f2bf_rne(x0 - bf2f(h0)), l1 = f2bf_rne(x1 - bf2f(h1));
            uhv[e] = (unsigned)h0 | ((unsigned)h1 << 16);
            ulv[e] = (unsigned)l0 | ((unsigned)l1 << 16);
        }
        *(uint4*)(ch + k * 64 + b * 8) = make_uint4(uhv[0], uhv[1], uhv[2], uhv[3]);
        *(uint4*)(cl + k * 64 + b * 8) = make_uint4(ulv[0], ulv[1], ulv[2], ulv[3]);
    }
}

// Kernel 1: MFMA screen. r17 change: staging via global_load_lds width=16
// with PRE-SWIZZLED global source + linear LDS dest (m173 pattern). The
// swizzle slot^=(row&7) is an involution, so the existing swizzled ds_reads
// see bit-identical bytes -> frozen numerics preserved. Register-fed float4
// gather/SSE/histogram epilogue for unflagged tokens (r16, PASSED).
__global__ __launch_bounds__(512) void vq_screen(
    const float*          __restrict__ ze,
    const float*          __restrict__ cb,
    const unsigned short* __restrict__ ch_g,
    const unsigned short* __restrict__ cl_g,
    const float*          __restrict__ h_g,
    float*                __restrict__ out,
    double*               __restrict__ sse_g,
    int*                  __restrict__ counts) {
    __shared__ __align__(16) char lds[2 * 16384 + 2 * 256 + 64];
    const int tid  = threadIdx.x;
    const int lane = tid & 63;
    const int wid  = tid >> 6;
    const int col  = lane & 15;
    const int grp  = lane >> 4;
    const int tbase = blockIdx.x * 256 + wid * 32;

    // pre-swizzled global source offset (bytes within an 8KB chunk):
    // linear LDS slot j=tid holds ch[swz(j)]; swz = involution (row,col^row&7)
    const int srow = tid >> 3, scol = tid & 7;
    const int srcoff = (srow * 8 + (scol ^ (srow & 7))) * 16;

    bf16x8 zh[2][2], zl[2][2];
#pragma unroll
    for (int tt = 0; tt < 2; ++tt)
#pragma unroll
        for (int s = 0; s < 2; ++s) {
            const float* zp = ze + (size_t)(tbase + tt * 16 + col) * 64 + s * 32 + grp * 8;
            float4 v0 = *(const float4*)(zp);
            float4 v1 = *(const float4*)(zp + 4);
            float zv[8] = {v0.x, v0.y, v0.z, v0.w, v1.x, v1.y, v1.z, v1.w};
            bf16x8 hfr, lfr;
#pragma unroll
            for (int j = 0; j < 8; ++j) {
                unsigned short hb = f2bf_rne(zv[j]);
                unsigned short lb = f2bf_rne(zv[j] - bf2f(hb));
                hfr[j] = (short)hb;
                lfr[j] = (short)lb;
            }
            zh[tt][s] = hfr;
            zl[tt][s] = lfr;
        }

    float m1[2] = {INFINITY, INFINITY}, m2[2] = {INFINITY, INFINITY};
    int   ki[2] = {0, 0};

    // staging: direct global->LDS DMA; LDS dest = wave-uniform base + lane*16
#define STAGE(cc, b)                                                           \
    do {                                                                       \
        __builtin_amdgcn_global_load_lds(                                      \
            (gas_t)((const char*)ch_g + (cc) * 8192 + srcoff),                 \
            (las_t)(lds + (b) * 16384 + wid * 1024), 16, 0, 0);                \
        __builtin_amdgcn_global_load_lds(                                      \
            (gas_t)((const char*)cl_g + (cc) * 8192 + srcoff),                 \
            (las_t)(lds + (b) * 16384 + 8192 + wid * 1024), 16, 0, 0);         \
        if (wid == 0)                                                          \
            __builtin_amdgcn_global_load_lds(                                  \
                (gas_t)(h_g + (cc) * 64 + lane),                               \
                (las_t)(lds + 32768 + (b) * 256), 4, 0, 0);                    \
    } while (0)

    STAGE(0, 0);
    __syncthreads();

    for (int cc = 0; cc < 16; ++cc) {
        int b = cc & 1;
        if (cc + 1 < 16) STAGE(cc + 1, b ^ 1);   // in flight across MFMA phase

        for (int ct = 0; ct < 4; ++ct) {
            const int arow = b * 16384 + ct * 2048 + col * 128;
            bf16x8 ach0 = *(const bf16x8*)(lds + arow + ((((0 * 4) + grp) ^ (col & 7)) << 4));
            bf16x8 ach1 = *(const bf16x8*)(lds + arow + ((((1 * 4) + grp) ^ (col & 7)) << 4));
            bf16x8 acl0 = *(const bf16x8*)(lds + arow + 8192 + ((((0 * 4) + grp) ^ (col & 7)) << 4));
            bf16x8 acl1 = *(const bf16x8*)(lds + arow + 8192 + ((((1 * 4) + grp) ^ (col & 7)) << 4));
            f32x4 hv = *(const f32x4*)(lds + 32768 + b * 256 + ct * 64 + grp * 16);

            f32x4 acc0 = hv, acc1 = hv;
            acc0 = __builtin_amdgcn_mfma_f32_16x16x32_bf16(ach0, zh[0][0], acc0, 0, 0, 0);
            acc1 = __builtin_amdgcn_mfma_f32_16x16x32_bf16(ach0, zh[1][0], acc1, 0, 0, 0);
            acc0 = __builtin_amdgcn_mfma_f32_16x16x32_bf16(ach1, zh[0][1], acc0, 0, 0, 0);
            acc1 = __builtin_amdgcn_mfma_f32_16x16x32_bf16(ach1, zh[1][1], acc1, 0, 0, 0);
            acc0 = __builtin_amdgcn_mfma_f32_16x16x32_bf16(ach0, zl[0][0], acc0, 0, 0, 0);
            acc1 = __builtin_amdgcn_mfma_f32_16x16x32_bf16(ach0, zl[1][0], acc1, 0, 0, 0);
            acc0 = __builtin_amdgcn_mfma_f32_16x16x32_bf16(ach1, zl[0][1], acc0, 0, 0, 0);
            acc1 = __builtin_amdgcn_mfma_f32_16x16x32_bf16(ach1, zl[1][1], acc1, 0, 0, 0);
            acc0 = __builtin_amdgcn_mfma_f32_16x16x32_bf16(acl0, zh[0][0], acc0, 0, 0, 0);
            acc1 = __builtin_amdgcn_mfma_f32_16x16x32_bf16(acl0, zh[1][0], acc1, 0, 0, 0);
            acc0 = __builtin_amdgcn_mfma_f32_16x16x32_bf16(acl1, zh[0][1], acc0, 0, 0, 0);
            acc1 = __builtin_amdgcn_mfma_f32_16x16x32_bf16(acl1, zh[1][1], acc1, 0, 0, 0);

            const int kb = cc * 64 + ct * 16 + grp * 4;
#pragma unroll
            for (int j = 0; j < 4; ++j) {
                float s0 = acc0[j], s1 = acc1[j];
                bool lt0 = s0 < m1[0], lt1 = s1 < m1[1];
                m2[0] = fminf(m2[0], fmaxf(s0, m1[0]));
                m2[1] = fminf(m2[1], fmaxf(s1, m1[1]));
                ki[0] = lt0 ? (kb + j) : ki[0];
                ki[1] = lt1 ? (kb + j) : ki[1];
                m1[0] = fminf(m1[0], s0);
                m1[1] = fminf(m1[1], s1);
            }
        }
        __syncthreads();   // compiler drains vmcnt here -> next buffer ready
    }

#pragma unroll
    for (int d = 16; d <= 32; d <<= 1) {
#pragma unroll
        for (int tt = 0; tt < 2; ++tt) {
            float om1 = __shfl_xor(m1[tt], d, 64);
            float om2 = __shfl_xor(m2[tt], d, 64);
            int   oki = __shfl_xor(ki[tt], d, 64);
            m2[tt] = fminf(fminf(m2[tt], om2), fmaxf(m1[tt], om1));
            ki[tt] = (om1 < m1[tt]) ? oki : ki[tt];
            m1[tt] = fminf(m1[tt], om1);
        }
    }
    // after butterfly, every lane holds m1/m2/ki for token col = lane&15
    unsigned flagpack = ((m2[0] - m1[0] < EPS_FLAG) ? 1u : 0u)
                      | ((m2[1] - m1[1] < EPS_FLAG) ? 2u : 0u);
    if (lane < 16) {
#pragma unroll
        for (int tt = 0; tt < 2; ++tt) {
            int t = tbase + tt * 16 + lane;
            bool flag = (flagpack >> tt) & 1u;
            out[OUT_IDX + t] = flag ? -(float)(ki[tt] + 1) : (float)ki[tt];
        }
    }

    // ---- register-fed float4 gather/SSE/histogram for UNFLAGGED tokens ----
    double lsse = 0.0;
    const int d4 = lane & 15;
#pragma unroll
    for (int iter = 0; iter < 8; ++iter) {
        const int j   = iter * 4 + grp;       // row in [0,32)
        const int tt  = iter >> 2;            // uniform per iter
        const int src = j & 15;
        int k = __shfl(ki[tt], src, 64);
        unsigned fp = __shfl(flagpack, src, 64);
        if (!((fp >> tt) & 1u)) {
            const int t = tbase + j;
            float4 q  = *(const float4*)(cb + k * DIM + d4 * 4);
            float4 zv = *(const float4*)(ze + (size_t)t * DIM + d4 * 4);
            *(float4*)(out + (size_t)t * DIM + d4 * 4) = q;
            double dx = (double)q.x - (double)zv.x;
            double dy = (double)q.y - (double)zv.y;
            double dz = (double)q.z - (double)zv.z;
            double dw = (double)q.w - (double)zv.w;
            lsse = fma(dx, dx, lsse); lsse = fma(dy, dy, lsse);
            lsse = fma(dz, dz, lsse); lsse = fma(dw, dw, lsse);
            if (d4 == 0) atomicAdd(&counts[k * 16], 1);   // one per row
        }
    }
#pragma unroll
    for (int off = 32; off > 0; off >>= 1)
        lsse += __shfl_down(lsse, off, 64);
    double* red = (double*)(lds + 33280);
    if (lane == 0) red[wid] = lsse;
    __syncthreads();
    if (tid == 0) {
        double bs = ((red[0] + red[1]) + (red[2] + red[3]))
                  + ((red[4] + red[5]) + (red[6] + red[7]));
        atomicAdd(sse_g, bs);
    }
}

// Kernel 2: rescue (r16 VERBATIM -- PASSED). Block owns 512 tokens, local
// worklist, LDS-staged full-codebook exact scan, end-to-end ownership,
// done-counter last-block finalize.
__global__ __launch_bounds__(512) void vq_rescue(
    const float* __restrict__ ze, const float* __restrict__ cb,
    const float* __restrict__ h_g, float* __restrict__ out,
    double* __restrict__ sse_g, int* __restrict__ counts,
    int* __restrict__ done) {
    __shared__ __align__(16) float4 cbl[512 * 17];          // 139,264 B
    __shared__ float zst[8][64];
    __shared__ unsigned long long keys[8][64];
    __shared__ float hl[NEMB];
    __shared__ int loc[512];
    __shared__ int nloc;
    __shared__ double red[8];
    __shared__ int flagS;
    const int tid  = threadIdx.x;
    const int lane = tid & 63;
    const int wid  = tid >> 6;
    const int tbase = blockIdx.x * 512;

    if (tid == 0) nloc = 0;
    for (int i = tid; i < NEMB; i += 512) hl[i] = h_g[i];
    __syncthreads();
    float fidx = out[OUT_IDX + tbase + tid];
    if (fidx < 0.0f) { int s = atomicAdd(&nloc, 1); loc[s] = tid; }
    __syncthreads();
    const int nq = nloc;
    double lsse = 0.0;

    if (nq > 0) {
        const float4* cb4 = (const float4*)cb;
        for (int hf = 0; hf < 2; ++hf) {
            __syncthreads();
#pragma unroll
            for (int j = 0; j < 16; ++j) {
                int f = tid + j * 512;
                int code = f >> 4, d4 = f & 15;
                cbl[code * 17 + d4] = cb4[(size_t)(hf * 512 + code) * 16 + d4];
            }
            __syncthreads();

            for (int i = wid; i < nq; i += 8) {
                const int t = tbase + loc[i];
                const int slot = i >> 3;

                zst[wid][lane] = ze[(size_t)t * 64 + lane];
                __builtin_amdgcn_wave_barrier();
                asm volatile("s_waitcnt lgkmcnt(0)" ::: "memory");
                __builtin_amdgcn_sched_barrier(0);

                float sz;
#define GZ(d) (zst[wid][d])
                NP_PAIRWISE_SQ64(GZ, sz);
#undef GZ

                float acc[8] = {0.f, 0.f, 0.f, 0.f, 0.f, 0.f, 0.f, 0.f};
                const float4* zr4 = (const float4*)zst[wid];
#pragma unroll
                for (int d4 = 0; d4 < 16; ++d4) {
                    float4 zq = zr4[d4];
#pragma unroll
                    for (int cc = 0; cc < 8; ++cc) {
                        float4 cv = cbl[(lane + 64 * cc) * 17 + d4];
                        acc[cc] = fmaf(cv.x, zq.x, acc[cc]);
                        acc[cc] = fmaf(cv.y, zq.y, acc[cc]);
                        acc[cc] = fmaf(cv.z, zq.z, acc[cc]);
                        acc[cc] = fmaf(cv.w, zq.w, acc[cc]);
                    }
                }
                unsigned long long key = ~0ull;
#pragma unroll
                for (int cc = 0; cc < 8; ++cc) {
                    unsigned k = (unsigned)(hf * 512 + lane + 64 * cc);
                    float dk = (sz + hl[k]) - 2.0f * acc[cc];   // frozen formula
                    unsigned long long c =
                        ((unsigned long long)__float_as_uint(dk) << 32) | k;
                    key = c < key ? c : key;
                }
#pragma unroll
                for (int dd = 1; dd < 64; dd <<= 1) {
                    unsigned long long o = __shfl_xor(key, dd, 64);
                    key = o < key ? o : key;
                }
                if (hf == 0) {
                    if (lane == 0) keys[wid][slot] = key;
                } else {
                    unsigned long long k0 = keys[wid][slot];  // LDS broadcast
                    if (k0 < key) key = k0;
                    int newk = (int)(unsigned)(key & 0xFFFFFFFFull);
                    float q  = cb[newk * 64 + lane];
                    float zv = zst[wid][lane];
                    out[(size_t)t * 64 + lane] = q;
                    double diff = (double)q - (double)zv;
                    lsse = fma(diff, diff, lsse);
                    if (lane == 0) {
                        out[OUT_IDX + t] = (float)newk;
                        atomicAdd(&counts[newk * 16], 1);
                    }
                }
            }
        }
    }

#pragma unroll
    for (int off = 32; off > 0; off >>= 1)
        lsse += __shfl_down(lsse, off, 64);
    if (lane == 0) red[wid] = lsse;
    __syncthreads();
    if (tid == 0) {
        double bs = ((red[0] + red[1]) + (red[2] + red[3]))
                  + ((red[4] + red[5]) + (red[6] + red[7]));
        if (bs != 0.0) atomicAdd(sse_g, bs);
        __threadfence();
        flagS = (atomicAdd(done, 1) == 255);
    }
    __syncthreads();

    if (flagS) {
        __threadfence();
        double* red2 = (double*)cbl;   // staging LDS dead here
        double local = 0.0;
        for (int k = tid; k < NEMB; k += 512) {
            int cv = __hip_atomic_load(&counts[k * 16], __ATOMIC_RELAXED, __HIP_MEMORY_SCOPE_AGENT);
            double p = (double)cv / (double)NTOK;
            local += p * log(p + 1e-10);
        }
        red2[tid] = local;
        __syncthreads();
        for (int s = 256; s > 0; s >>= 1) {
            if (tid < s) red2[tid] += red2[tid + s];
            __syncthreads();
        }
        if (tid == 0) {
            double sv = __hip_atomic_load(sse_g, __ATOMIC_RELAXED, __HIP_MEMORY_SCOPE_AGENT);
            double mse = sv / ((double)NTOK * (double)DIM);
            out[OUT_LOSS] = (float)(1.25 * mse);
            out[OUT_PERP] = (float)exp(-red2[0]);
        }
    }
}

extern "C" void kernel_launch(void* const* d_in, const int* in_sizes, int n_in,
                              void* d_out, int out_size, void* d_ws, size_t ws_size,
                              hipStream_t stream) {
    const float* ze = (const float*)d_in[0];
    const float* cb = (const float*)d_in[1];
    float* out = (float*)d_out;

    char* w = (char*)d_ws;
    double*         sse    = (double*)w;                     // @0
    int*            counts = (int*)(w + 64);                 // 64 KiB (padded)
    int*            done   = (int*)(w + 65600);
    float*          h      = (float*)(w + 65664);            // 4 KiB
    unsigned short* ch     = (unsigned short*)(w + 69760);   // 128 KiB
    unsigned short* cl     = (unsigned short*)(w + 200832);  // 128 KiB

    vq_prep<<<NEMB / 256, 256, 0, stream>>>(cb, h, ch, cl, sse, counts, done);
    vq_screen<<<NTOK / 256, 512, 0, stream>>>(ze, cb, ch, cl, h, out, sse, counts);
    vq_rescue<<<NTOK / 512, 512, 0, stream>>>(ze, cb, h, out, sse, counts, done);
}

// Round 18
// 125.571 us; speedup vs baseline: 2.1340x; 1.0052x over previous
//
#include <hip/hip_runtime.h>
#include <math.h>

// VectorQuantizer: N=131072 tokens, K=1024 codes, D=64, fp32.
// Out layout (flat): z_q_st[N*D] | loss | perplexity | indices[N] (as f32)
#define NTOK 131072
#define NEMB 1024
#define DIM  64
#define OUT_LOSS (NTOK * DIM)
#define OUT_PERP (OUT_LOSS + 1)
#define OUT_IDX  (OUT_LOSS + 2)

#define EPS_FLAG 6e-5f   // screen ambiguity margin (frozen; passed r3-r17)

typedef short bf16x8 __attribute__((ext_vector_type(8)));
typedef float f32x4  __attribute__((ext_vector_type(4)));
typedef const __attribute__((address_space(1))) void* gas_t;
typedef __attribute__((address_space(3))) void* las_t;

// ---- numpy fp32 semantics helpers (frozen from round 2 -- PASSED) ----------
__device__ __forceinline__ float sqb(float x) {
    float y = x * x;
    asm volatile("" : "+v"(y));
    return y;
}
// numpy pairwise_sum for n=64 contiguous: 8 accumulators stride 8, then
// ((r0+r1)+(r2+r3))+((r4+r5)+(r6+r7)).
#define NP_PAIRWISE_SQ64(GET, RES)                                     \
    do {                                                               \
        float r0 = sqb(GET(0)), r1 = sqb(GET(1)), r2 = sqb(GET(2)),    \
              r3 = sqb(GET(3)), r4 = sqb(GET(4)), r5 = sqb(GET(5)),    \
              r6 = sqb(GET(6)), r7 = sqb(GET(7));                      \
        _Pragma("unroll")                                              \
        for (int i = 8; i < 64; i += 8) {                              \
            r0 += sqb(GET(i + 0)); r1 += sqb(GET(i + 1));              \
            r2 += sqb(GET(i + 2)); r3 += sqb(GET(i + 3));              \
            r4 += sqb(GET(i + 4)); r5 += sqb(GET(i + 5));              \
            r6 += sqb(GET(i + 6)); r7 += sqb(GET(i + 7));              \
        }                                                              \
        RES = ((r0 + r1) + (r2 + r3)) + ((r4 + r5) + (r6 + r7));       \
    } while (0)

__device__ __forceinline__ unsigned short f2bf_rne(float x) {
    unsigned u = __float_as_uint(x);
    u += 0x7FFFu + ((u >> 16) & 1u);   // round-to-nearest-even
    return (unsigned short)(u >> 16);
}
__device__ __forceinline__ float bf2f(unsigned short b) {
    return __uint_as_float(((unsigned)b) << 16);
}

// ws layout (bytes):
//   0:      sse double
//   64:     counts int[1024*16]  (64 KiB, one counter per 64B line)
//   65600:  done int
//   65664:  h float[1024]        (4 KiB)
//   69760:  ch bf16[1024*64]     (128 KiB)
//   200832: cl bf16[1024*64]     (128 KiB)

// Kernel 0: h[k] np-exact; ch/cl bf16 split of (-2c); block 0 zeroes accums.
__global__ void vq_prep(const float* __restrict__ cb, float* __restrict__ h,
                        unsigned short* __restrict__ ch, unsigned short* __restrict__ cl,
                        double* __restrict__ sse, int* __restrict__ counts,
                        int* __restrict__ done) {
    if (blockIdx.x == 0) {
        if (threadIdx.x == 0) { *sse = 0.0; *done = 0; }
        for (int i = threadIdx.x; i < NEMB * 16; i += 256) counts[i] = 0;
    }
    int k = blockIdx.x * 256 + threadIdx.x;
    if (k >= NEMB) return;
    float c[64];
    const float4* p = (const float4*)(cb + k * DIM);
#pragma unroll
    for (int q = 0; q < 16; ++q) {
        float4 v = p[q];
        c[4 * q] = v.x; c[4 * q + 1] = v.y; c[4 * q + 2] = v.z; c[4 * q + 3] = v.w;
    }
    float hk;
#define GETC(d) (c[d])
    NP_PAIRWISE_SQ64(GETC, hk);
#undef GETC
    h[k] = hk;
#pragma unroll
    for (int b = 0; b < 8; ++b) {
        unsigned uhv[4], ulv[4];
#pragma unroll
        for (int e = 0; e < 4; ++e) {
            float x0 = -2.0f * c[b * 8 + e * 2 + 0];
            float x1 = -2.0f * c[b * 8 + e * 2 + 1];
            unsigned short h0 = f2bf_rne(x0), h1 = f2bf_rne(x1);
            unsigned short l0 = f2bf_rne(x0 - bf2f(h0)), l1 = f2bf_rne(x1 - bf2f(h1));
            uhv[e] = (unsigned)h0 | ((unsigned)h1 << 16);
            ulv[e] = (unsigned)l0 | ((unsigned)l1 << 16);
        }
        *(uint4*)(ch + k * 64 + b * 8) = make_uint4(uhv[0], uhv[1], uhv[2], uhv[3]);
        *(uint4*)(cl + k * 64 + b * 8) = make_uint4(ulv[0], ulv[1], ulv[2], ulv[3]);
    }
}

// Kernel 1: MFMA screen. r18 change: 3-buffer counted-vmcnt pipeline (m201
// pattern) -- staging runs 2 chunks ahead; chunk boundary = s_waitcnt vmcnt(2)
// + raw s_barrier + sched_barrier(0) (NOT __syncthreads -> no vmcnt(0) drain).
// h preloaded to LDS once (hv via ds_read, keeps vmcnt counts exact: 2/STAGE).
// Staged bytes + swizzled ds_reads + MFMA inputs bit-identical to r17
// (frozen numerics). Register-fed float4 gather epilogue (r16, PASSED).
__global__ __launch_bounds__(512) void vq_screen(
    const float*          __restrict__ ze,
    const float*          __restrict__ cb,
    const unsigned short* __restrict__ ch_g,
    const unsigned short* __restrict__ cl_g,
    const float*          __restrict__ h_g,
    float*                __restrict__ out,
    double*               __restrict__ sse_g,
    int*                  __restrict__ counts) {
    // LDS: 3 x 16KB chunk buffers | h 4KB @49152 | red 64B @53312
    __shared__ __align__(16) char lds[53376];
    const int tid  = threadIdx.x;
    const int lane = tid & 63;
    const int wid  = tid >> 6;
    const int col  = lane & 15;
    const int grp  = lane >> 4;
    const int tbase = blockIdx.x * 256 + wid * 32;

    // pre-swizzled global source offset (involution row,col^row&7 -- r17)
    const int srow = tid >> 3, scol = tid & 7;
    const int srcoff = (srow * 8 + (scol ^ (srow & 7))) * 16;

    bf16x8 zh[2][2], zl[2][2];
#pragma unroll
    for (int tt = 0; tt < 2; ++tt)
#pragma unroll
        for (int s = 0; s < 2; ++s) {
            const float* zp = ze + (size_t)(tbase + tt * 16 + col) * 64 + s * 32 + grp * 8;
            float4 v0 = *(const float4*)(zp);
            float4 v1 = *(const float4*)(zp + 4);
            float zv[8] = {v0.x, v0.y, v0.z, v0.w, v1.x, v1.y, v1.z, v1.w};
            bf16x8 hfr, lfr;
#pragma unroll
            for (int j = 0; j < 8; ++j) {
                unsigned short hb = f2bf_rne(zv[j]);
                unsigned short lb = f2bf_rne(zv[j] - bf2f(hb));
                hfr[j] = (short)hb;
                lfr[j] = (short)lb;
            }
            zh[tt][s] = hfr;
            zl[tt][s] = lfr;
        }

    float m1[2] = {INFINITY, INFINITY}, m2[2] = {INFINITY, INFINITY};
    int   ki[2] = {0, 0};

    // STAGE = exactly 2 DMA loads per thread (uniform across waves)
#define STAGE(cc, b)                                                           \
    do {                                                                       \
        __builtin_amdgcn_global_load_lds(                                      \
            (gas_t)((const char*)ch_g + (cc) * 8192 + srcoff),                 \
            (las_t)(lds + (b) * 16384 + wid * 1024), 16, 0, 0);                \
        __builtin_amdgcn_global_load_lds(                                      \
            (gas_t)((const char*)cl_g + (cc) * 8192 + srcoff),                 \
            (las_t)(lds + (b) * 16384 + 8192 + wid * 1024), 16, 0, 0);         \
    } while (0)

#define COMPUTE(cc, b)                                                         \
    do {                                                                       \
        _Pragma("unroll")                                                      \
        for (int ct = 0; ct < 4; ++ct) {                                       \
            const int arow = (b) * 16384 + ct * 2048 + col * 128;              \
            bf16x8 ach0 = *(const bf16x8*)(lds + arow + ((((0 * 4) + grp) ^ (col & 7)) << 4)); \
            bf16x8 ach1 = *(const bf16x8*)(lds + arow + ((((1 * 4) + grp) ^ (col & 7)) << 4)); \
            bf16x8 acl0 = *(const bf16x8*)(lds + arow + 8192 + ((((0 * 4) + grp) ^ (col & 7)) << 4)); \
            bf16x8 acl1 = *(const bf16x8*)(lds + arow + 8192 + ((((1 * 4) + grp) ^ (col & 7)) << 4)); \
            f32x4 hv = *(const f32x4*)(lds + 49152 + (cc) * 256 + ct * 64 + grp * 16); \
            f32x4 acc0 = hv, acc1 = hv;                                        \
            acc0 = __builtin_amdgcn_mfma_f32_16x16x32_bf16(ach0, zh[0][0], acc0, 0, 0, 0); \
            acc1 = __builtin_amdgcn_mfma_f32_16x16x32_bf16(ach0, zh[1][0], acc1, 0, 0, 0); \
            acc0 = __builtin_amdgcn_mfma_f32_16x16x32_bf16(ach1, zh[0][1], acc0, 0, 0, 0); \
            acc1 = __builtin_amdgcn_mfma_f32_16x16x32_bf16(ach1, zh[1][1], acc1, 0, 0, 0); \
            acc0 = __builtin_amdgcn_mfma_f32_16x16x32_bf16(ach0, zl[0][0], acc0, 0, 0, 0); \
            acc1 = __builtin_amdgcn_mfma_f32_16x16x32_bf16(ach0, zl[1][0], acc1, 0, 0, 0); \
            acc0 = __builtin_amdgcn_mfma_f32_16x16x32_bf16(ach1, zl[0][1], acc0, 0, 0, 0); \
            acc1 = __builtin_amdgcn_mfma_f32_16x16x32_bf16(ach1, zl[1][1], acc1, 0, 0, 0); \
            acc0 = __builtin_amdgcn_mfma_f32_16x16x32_bf16(acl0, zh[0][0], acc0, 0, 0, 0); \
            acc1 = __builtin_amdgcn_mfma_f32_16x16x32_bf16(acl0, zh[1][0], acc1, 0, 0, 0); \
            acc0 = __builtin_amdgcn_mfma_f32_16x16x32_bf16(acl1, zh[0][1], acc0, 0, 0, 0); \
            acc1 = __builtin_amdgcn_mfma_f32_16x16x32_bf16(acl1, zh[1][1], acc1, 0, 0, 0); \
            const int kb = (cc) * 64 + ct * 16 + grp * 4;                      \
            _Pragma("unroll")                                                  \
            for (int j = 0; j < 4; ++j) {                                      \
                float s0 = acc0[j], s1 = acc1[j];                              \
                bool lt0 = s0 < m1[0], lt1 = s1 < m1[1];                       \
                m2[0] = fminf(m2[0], fmaxf(s0, m1[0]));                        \
                m2[1] = fminf(m2[1], fmaxf(s1, m1[1]));                        \
                ki[0] = lt0 ? (kb + j) : ki[0];                                \
                ki[1] = lt1 ? (kb + j) : ki[1];                                \
                m1[0] = fminf(m1[0], s0);                                      \
                m1[1] = fminf(m1[1], s1);                                      \
            }                                                                  \
        }                                                                      \
    } while (0)

    // chunk boundary: counted wait (loads for cc+1 stay in flight) + barrier
#define CHUNK(cc, W)                                                           \
    do {                                                                       \
        asm volatile("s_waitcnt vmcnt(" #W ")" ::: "memory");                  \
        __builtin_amdgcn_s_barrier();                                          \
        __builtin_amdgcn_sched_barrier(0);                                     \
        if ((cc) + 2 < 16) STAGE((cc) + 2, ((cc) + 2) % 3);                    \
        COMPUTE(cc, (cc) % 3);                                                 \
    } while (0)

    // prologue: h (2 uniform width-4 DMAs, oldest) + chunks 0,1
    __builtin_amdgcn_global_load_lds((gas_t)(h_g + tid),
                                     (las_t)(lds + 49152 + wid * 256), 4, 0, 0);
    __builtin_amdgcn_global_load_lds((gas_t)(h_g + 512 + tid),
                                     (las_t)(lds + 49152 + 2048 + wid * 256), 4, 0, 0);
    STAGE(0, 0);
    STAGE(1, 1);

    CHUNK(0, 2);  CHUNK(1, 2);  CHUNK(2, 2);  CHUNK(3, 2);
    CHUNK(4, 2);  CHUNK(5, 2);  CHUNK(6, 2);  CHUNK(7, 2);
    CHUNK(8, 2);  CHUNK(9, 2);  CHUNK(10, 2); CHUNK(11, 2);
    CHUNK(12, 2); CHUNK(13, 2); CHUNK(14, 2); CHUNK(15, 0);

#pragma unroll
    for (int d = 16; d <= 32; d <<= 1) {
#pragma unroll
        for (int tt = 0; tt < 2; ++tt) {
            float om1 = __shfl_xor(m1[tt], d, 64);
            float om2 = __shfl_xor(m2[tt], d, 64);
            int   oki = __shfl_xor(ki[tt], d, 64);
            m2[tt] = fminf(fminf(m2[tt], om2), fmaxf(m1[tt], om1));
            ki[tt] = (om1 < m1[tt]) ? oki : ki[tt];
            m1[tt] = fminf(m1[tt], om1);
        }
    }
    // after butterfly, every lane holds m1/m2/ki for token col = lane&15
    unsigned flagpack = ((m2[0] - m1[0] < EPS_FLAG) ? 1u : 0u)
                      | ((m2[1] - m1[1] < EPS_FLAG) ? 2u : 0u);
    if (lane < 16) {
#pragma unroll
        for (int tt = 0; tt < 2; ++tt) {
            int t = tbase + tt * 16 + lane;
            bool flag = (flagpack >> tt) & 1u;
            out[OUT_IDX + t] = flag ? -(float)(ki[tt] + 1) : (float)ki[tt];
        }
    }

    // ---- register-fed float4 gather/SSE/histogram for UNFLAGGED tokens ----
    double lsse = 0.0;
    const int d4 = lane & 15;
#pragma unroll
    for (int iter = 0; iter < 8; ++iter) {
        const int j   = iter * 4 + grp;       // row in [0,32)
        const int tt  = iter >> 2;            // uniform per iter
        const int src = j & 15;
        int k = __shfl(ki[tt], src, 64);
        unsigned fp = __shfl(flagpack, src, 64);
        if (!((fp >> tt) & 1u)) {
            const int t = tbase + j;
            float4 q  = *(const float4*)(cb + k * DIM + d4 * 4);
            float4 zv = *(const float4*)(ze + (size_t)t * DIM + d4 * 4);
            *(float4*)(out + (size_t)t * DIM + d4 * 4) = q;
            double dx = (double)q.x - (double)zv.x;
            double dy = (double)q.y - (double)zv.y;
            double dz = (double)q.z - (double)zv.z;
            double dw = (double)q.w - (double)zv.w;
            lsse = fma(dx, dx, lsse); lsse = fma(dy, dy, lsse);
            lsse = fma(dz, dz, lsse); lsse = fma(dw, dw, lsse);
            if (d4 == 0) atomicAdd(&counts[k * 16], 1);   // one per row
        }
    }
#pragma unroll
    for (int off = 32; off > 0; off >>= 1)
        lsse += __shfl_down(lsse, off, 64);
    double* red = (double*)(lds + 53312);
    if (lane == 0) red[wid] = lsse;
    __syncthreads();
    if (tid == 0) {
        double bs = ((red[0] + red[1]) + (red[2] + red[3]))
                  + ((red[4] + red[5]) + (red[6] + red[7]));
        atomicAdd(sse_g, bs);
    }
}

// Kernel 2: rescue (r16/r17 VERBATIM -- PASSED). Block owns 512 tokens, local
// worklist, LDS-staged full-codebook exact scan, end-to-end ownership,
// done-counter last-block finalize.
__global__ __launch_bounds__(512) void vq_rescue(
    const float* __restrict__ ze, const float* __restrict__ cb,
    const float* __restrict__ h_g, float* __restrict__ out,
    double* __restrict__ sse_g, int* __restrict__ counts,
    int* __restrict__ done) {
    __shared__ __align__(16) float4 cbl[512 * 17];          // 139,264 B
    __shared__ float zst[8][64];
    __shared__ unsigned long long keys[8][64];
    __shared__ float hl[NEMB];
    __shared__ int loc[512];
    __shared__ int nloc;
    __shared__ double red[8];
    __shared__ int flagS;
    const int tid  = threadIdx.x;
    const int lane = tid & 63;
    const int wid  = tid >> 6;
    const int tbase = blockIdx.x * 512;

    if (tid == 0) nloc = 0;
    for (int i = tid; i < NEMB; i += 512) hl[i] = h_g[i];
    __syncthreads();
    float fidx = out[OUT_IDX + tbase + tid];
    if (fidx < 0.0f) { int s = atomicAdd(&nloc, 1); loc[s] = tid; }
    __syncthreads();
    const int nq = nloc;
    double lsse = 0.0;

    if (nq > 0) {
        const float4* cb4 = (const float4*)cb;
        for (int hf = 0; hf < 2; ++hf) {
            __syncthreads();
#pragma unroll
            for (int j = 0; j < 16; ++j) {
                int f = tid + j * 512;
                int code = f >> 4, d4 = f & 15;
                cbl[code * 17 + d4] = cb4[(size_t)(hf * 512 + code) * 16 + d4];
            }
            __syncthreads();

            for (int i = wid; i < nq; i += 8) {
                const int t = tbase + loc[i];
                const int slot = i >> 3;

                zst[wid][lane] = ze[(size_t)t * 64 + lane];
                __builtin_amdgcn_wave_barrier();
                asm volatile("s_waitcnt lgkmcnt(0)" ::: "memory");
                __builtin_amdgcn_sched_barrier(0);

                float sz;
#define GZ(d) (zst[wid][d])
                NP_PAIRWISE_SQ64(GZ, sz);
#undef GZ

                float acc[8] = {0.f, 0.f, 0.f, 0.f, 0.f, 0.f, 0.f, 0.f};
                const float4* zr4 = (const float4*)zst[wid];
#pragma unroll
                for (int d4 = 0; d4 < 16; ++d4) {
                    float4 zq = zr4[d4];
#pragma unroll
                    for (int cc = 0; cc < 8; ++cc) {
                        float4 cv = cbl[(lane + 64 * cc) * 17 + d4];
                        acc[cc] = fmaf(cv.x, zq.x, acc[cc]);
                        acc[cc] = fmaf(cv.y, zq.y, acc[cc]);
                        acc[cc] = fmaf(cv.z, zq.z, acc[cc]);
                        acc[cc] = fmaf(cv.w, zq.w, acc[cc]);
                    }
                }
                unsigned long long key = ~0ull;
#pragma unroll
                for (int cc = 0; cc < 8; ++cc) {
                    unsigned k = (unsigned)(hf * 512 + lane + 64 * cc);
                    float dk = (sz + hl[k]) - 2.0f * acc[cc];   // frozen formula
                    unsigned long long c =
                        ((unsigned long long)__float_as_uint(dk) << 32) | k;
                    key = c < key ? c : key;
                }
#pragma unroll
                for (int dd = 1; dd < 64; dd <<= 1) {
                    unsigned long long o = __shfl_xor(key, dd, 64);
                    key = o < key ? o : key;
                }
                if (hf == 0) {
                    if (lane == 0) keys[wid][slot] = key;
                } else {
                    unsigned long long k0 = keys[wid][slot];  // LDS broadcast
                    if (k0 < key) key = k0;
                    int newk = (int)(unsigned)(key & 0xFFFFFFFFull);
                    float q  = cb[newk * 64 + lane];
                    float zv = zst[wid][lane];
                    out[(size_t)t * 64 + lane] = q;
                    double diff = (double)q - (double)zv;
                    lsse = fma(diff, diff, lsse);
                    if (lane == 0) {
                        out[OUT_IDX + t] = (float)newk;
                        atomicAdd(&counts[newk * 16], 1);
                    }
                }
            }
        }
    }

#pragma unroll
    for (int off = 32; off > 0; off >>= 1)
        lsse += __shfl_down(lsse, off, 64);
    if (lane == 0) red[wid] = lsse;
    __syncthreads();
    if (tid == 0) {
        double bs = ((red[0] + red[1]) + (red[2] + red[3]))
                  + ((red[4] + red[5]) + (red[6] + red[7]));
        if (bs != 0.0) atomicAdd(sse_g, bs);
        __threadfence();
        flagS = (atomicAdd(done, 1) == 255);
    }
    __syncthreads();

    if (flagS) {
        __threadfence();
        double* red2 = (double*)cbl;   // staging LDS dead here
        double local = 0.0;
        for (int k = tid; k < NEMB; k += 512) {
            int cv = __hip_atomic_load(&counts[k * 16], __ATOMIC_RELAXED, __HIP_MEMORY_SCOPE_AGENT);
            double p = (double)cv / (double)NTOK;
            local += p * log(p + 1e-10);
        }
        red2[tid] = local;
        __syncthreads();
        for (int s = 256; s > 0; s >>= 1) {
            if (tid < s) red2[tid] += red2[tid + s];
            __syncthreads();
        }
        if (tid == 0) {
            double sv = __hip_atomic_load(sse_g, __ATOMIC_RELAXED, __HIP_MEMORY_SCOPE_AGENT);
            double mse = sv / ((double)NTOK * (double)DIM);
            out[OUT_LOSS] = (float)(1.25 * mse);
            out[OUT_PERP] = (float)exp(-red2[0]);
        }
    }
}

extern "C" void kernel_launch(void* const* d_in, const int* in_sizes, int n_in,
                              void* d_out, int out_size, void* d_ws, size_t ws_size,
                              hipStream_t stream) {
    const float* ze = (const float*)d_in[0];
    const float* cb = (const float*)d_in[1];
    float* out = (float*)d_out;

    char* w = (char*)d_ws;
    double*         sse    = (double*)w;                     // @0
    int*            counts = (int*)(w + 64);                 // 64 KiB (padded)
    int*            done   = (int*)(w + 65600);
    float*          h      = (float*)(w + 65664);            // 4 KiB
    unsigned short* ch     = (unsigned short*)(w + 69760);   // 128 KiB
    unsigned short* cl     = (unsigned short*)(w + 200832);  // 128 KiB

    vq_prep<<<NEMB / 256, 256, 0, stream>>>(cb, h, ch, cl, sse, counts, done);
    vq_screen<<<NTOK / 256, 512, 0, stream>>>(ze, cb, ch, cl, h, out, sse, counts);
    vq_rescue<<<NTOK / 512, 512, 0, stream>>>(ze, cb, h, out, sse, counts, done);
}